// Round 4
// baseline (341.794 us; speedup 1.0000x reference)
//
#include <hip/hip_runtime.h>
#include <hip/hip_fp16.h>
#include <math.h>

#define T_LEN 8192
#define CHN 128
#define BATCH 16
#define NKCHUNK 16   // k-chunk = 512 = 16 tiles of 32

typedef short bf16x8 __attribute__((ext_vector_type(8)));
typedef float f32x16 __attribute__((ext_vector_type(16)));

#define SIN8 0.3826834323650898f
#define COS8 0.9238795325112868f

__device__ __forceinline__ ushort f2bf(float f) {
    unsigned u = __float_as_uint(f);
    unsigned r = (u + 0x7fffu + ((u >> 16) & 1u)) >> 16;
    return (ushort)r;
}

__device__ __forceinline__ float2 cadd(float2 a, float2 b) { return make_float2(a.x + b.x, a.y + b.y); }
__device__ __forceinline__ float2 csub(float2 a, float2 b) { return make_float2(a.x - b.x, a.y - b.y); }
__device__ __forceinline__ float2 cmul(float2 a, float2 b) {
    return make_float2(a.x * b.x - a.y * b.y, a.x * b.y + a.y * b.x);
}

__device__ __forceinline__ void r4f(float2 x0, float2 x1, float2 x2, float2 x3,
                                    float2 wa, float2 wb, float2 wc,
                                    float2& y0, float2& y1, float2& y2, float2& y3) {
    float2 t0 = cadd(x0, x2), t1 = csub(x0, x2);
    float2 t2 = cadd(x1, x3), t3 = csub(x1, x3);
    y0 = cadd(t0, t2);
    y1 = cmul(csub(t0, t2), wb);
    y2 = cmul(make_float2(t1.x + t3.y, t1.y - t3.x), wa);
    y3 = cmul(make_float2(t1.x - t3.y, t1.y + t3.x), wc);
}

__device__ __forceinline__ void r4i(float2 x0, float2 x1, float2 x2, float2 x3,
                                    float2 wa, float2 wb, float2 wc,
                                    float2& y0, float2& y1, float2& y2, float2& y3) {
    float2 a1 = cmul(x1, wb);
    float2 a2 = cmul(x2, wa);
    float2 a3 = cmul(x3, wc);
    float2 u0 = cadd(x0, a1), u1 = csub(x0, a1);
    float2 p = cadd(a2, a3);
    float2 m = make_float2(-(a2.y - a3.y), a2.x - a3.x);
    y0 = cadd(u0, p); y2 = csub(u0, p);
    y1 = cadd(u1, m); y3 = csub(u1, m);
}

// radix-8 DIF butterfly, twiddle angle base (sn,cs) = sincos(-pi*j/(4Q)) for fwd
__device__ __forceinline__ void r8f(const float2* x, float sn, float cs, float2* y) {
    const float r22 = 0.70710678118654752f;
    float2 w1 = make_float2(cs, sn);
    float2 w2 = make_float2(cs * cs - sn * sn, 2.f * cs * sn);
    float2 w4 = cmul(w2, w2);
    float2 w6 = cmul(w4, w2);
    float2 u0 = cadd(x[0], x[4]), u1 = cadd(x[1], x[5]), u2 = cadd(x[2], x[6]), u3 = cadd(x[3], x[7]);
    float2 e0 = cmul(csub(x[0], x[4]), w1);
    float2 e1 = cmul(csub(x[1], x[5]), w1);
    float2 e2 = cmul(csub(x[2], x[6]), w1);
    float2 e3 = cmul(csub(x[3], x[7]), w1);
    float2 v0 = e0;
    float2 v1 = make_float2(r22 * (e1.x + e1.y), r22 * (e1.y - e1.x));
    float2 v2 = make_float2(e2.y, -e2.x);
    float2 v3 = make_float2(r22 * (e3.y - e3.x), -r22 * (e3.x + e3.y));
    r4f(u0, u1, u2, u3, w2, w4, w6, y[0], y[1], y[2], y[3]);
    r4f(v0, v1, v2, v3, w2, w4, w6, y[4], y[5], y[6], y[7]);
}

// radix-8 DIT butterfly (inverse), twiddle angle base (sn,cs) = sincos(+pi*j/(4Q))
__device__ __forceinline__ void r8i(const float2* x, float sn, float cs, float2* y) {
    const float r22 = 0.70710678118654752f;
    float2 w1 = make_float2(cs, sn);
    float2 w2 = make_float2(cs * cs - sn * sn, 2.f * cs * sn);
    float2 w4 = cmul(w2, w2);
    float2 w6 = cmul(w4, w2);
    float2 g0, g1, g2, g3, g4, g5, g6, g7;
    r4i(x[0], x[1], x[2], x[3], w2, w4, w6, g0, g1, g2, g3);
    r4i(x[4], x[5], x[6], x[7], w2, w4, w6, g4, g5, g6, g7);
    float2 t0 = cmul(g4, w1);
    float2 e1 = cmul(g5, w1);
    float2 e2 = cmul(g6, w1);
    float2 e3 = cmul(g7, w1);
    float2 t1 = make_float2(r22 * (e1.x - e1.y), r22 * (e1.x + e1.y));
    float2 t2 = make_float2(-e2.y, e2.x);
    float2 t3 = make_float2(-r22 * (e3.x + e3.y), r22 * (e3.x - e3.y));
    y[0] = cadd(g0, t0); y[4] = csub(g0, t0);
    y[1] = cadd(g1, t1); y[5] = csub(g1, t1);
    y[2] = cadd(g2, t2); y[6] = csub(g2, t2);
    y[3] = cadd(g3, t3); y[7] = csub(g3, t3);
}

// One block per (b,c) row. 3 LDS radix-8 passes (dist 4096..16), register-local
// middle (dist 8,4,2 + mask-fused dist 1 + inverse dist 2,4,8), 3 inverse LDS
// passes, normalize, store bf16 cos/sin into TILED layout:
// zt[b][kb=k/32][plane(c,s)][row(128)][k%32]  -> 16 KB contiguous per chunk.
__global__ __launch_bounds__(512, 4) void fft_analytic_kernel(const float* __restrict__ x,
                                                              ushort* __restrict__ zt) {
    __shared__ __align__(16) float2 buf[T_LEN];   // 64 KiB
    const int tid = threadIdx.x;
    const int row = blockIdx.x;
    const float* xr = x + ((size_t)row << 13);

    for (int s = 0; s < 4; ++s) {
        int idx = tid + (s << 9);                 // float4 index, 2048 total
        float4 v = *(const float4*)(xr + idx * 4);
        *(float4*)&buf[idx * 4]     = make_float4(v.x, 0.f, v.y, 0.f);
        *(float4*)&buf[idx * 4 + 2] = make_float4(v.z, 0.f, v.w, 0.f);
    }
    __syncthreads();

    // forward LDS passes: Q = 1024, 128, 16 (radix-2 distances 4096..16)
    for (int pq = 0; pq < 3; ++pq) {
        const int Q = 1024 >> (3 * pq);
        const float astep = -(float)M_PI / (float)(4 * Q);
        for (int s = 0; s < 2; ++s) {
            const int g = tid + (s << 9);
            const int j = g & (Q - 1);
            const int i = ((g & ~(Q - 1)) << 3) | j;
            float2 xx[8], yy[8];
#pragma unroll
            for (int c = 0; c < 8; ++c) xx[c] = buf[i + c * Q];
            float sn, cs;
            __sincosf(astep * (float)j, &sn, &cs);
            r8f(xx, sn, cs, yy);
#pragma unroll
            for (int c = 0; c < 8; ++c) buf[i + c * Q] = yy[c];
        }
        __syncthreads();
    }

    // register-local middle: thread owns elements [16*tid, 16*tid+16)
    {
        float2 v[16];
        float4* bb = (float4*)buf;                // float4 index = pair of float2
#pragma unroll
        for (int p = 0; p < 8; ++p) {             // lane-staggered, conflict-free
            int pp = (p + tid) & 7;
            float4 f = bb[8 * tid + pp];
            v[2 * pp]     = make_float2(f.x, f.y);
            v[2 * pp + 1] = make_float2(f.z, f.w);
        }
        float2 xe[8], xo[8], E[8], O[8], t[8];
#pragma unroll
        for (int c = 0; c < 8; ++c) { xe[c] = v[2 * c]; xo[c] = v[2 * c + 1]; }
        r8f(xe, 0.f, 1.f, E);                     // fwd Q=2, j=0 (unity twiddles)
        r8f(xo, -SIN8, COS8, O);                  // fwd Q=2, j=1
#pragma unroll
        for (int c = 0; c < 8; ++c) t[c] = cadd(E[c], O[c]);   // dist-1 + mask fuse
        r8i(t, 0.f, 1.f, xe);                     // inv Q=2, j=0
        r8i(t, SIN8, COS8, xo);                   // inv Q=2, j=1
#pragma unroll
        for (int c = 0; c < 8; ++c) { v[2 * c] = xe[c]; v[2 * c + 1] = xo[c]; }
#pragma unroll
        for (int p = 0; p < 8; ++p) {
            int pp = (p + tid) & 7;
            bb[8 * tid + pp] = make_float4(v[2 * pp].x, v[2 * pp].y,
                                           v[2 * pp + 1].x, v[2 * pp + 1].y);
        }
    }
    __syncthreads();

    // inverse LDS passes: Q = 16, 128, 1024 (radix-2 distances 16..4096)
    for (int pq = 0; pq < 3; ++pq) {
        const int Q = 16 << (3 * pq);
        const float astep = (float)M_PI / (float)(4 * Q);
        for (int s = 0; s < 2; ++s) {
            const int g = tid + (s << 9);
            const int j = g & (Q - 1);
            const int i = ((g & ~(Q - 1)) << 3) | j;
            float2 xx[8], yy[8];
#pragma unroll
            for (int c = 0; c < 8; ++c) xx[c] = buf[i + c * Q];
            float sn, cs;
            __sincosf(astep * (float)j, &sn, &cs);
            r8i(xx, sn, cs, yy);
#pragma unroll
            for (int c = 0; c < 8; ++c) buf[i + c * Q] = yy[c];
        }
        __syncthreads();
    }

    // normalize to unit modulus, store bf16 planes into tiled layout
    const int bb_ = row >> 7, cc = row & 127;
    ushort* ztb = zt + (((size_t)bb_ * 256) << 13);   // b * 256 chunks * 8192 ushorts
    for (int s = 0; s < 8; ++s) {
        int tt = tid + (s << 9);                  // handles k = 2tt, 2tt+1
        float4 two = *(const float4*)&buf[tt * 2];
        float n0 = two.x * two.x + two.y * two.y;
        float n1 = two.z * two.z + two.w * two.w;
        float c0 = 1.f, s0 = 0.f, c1 = 1.f, s1 = 0.f;
        if (n0 > 0.f) { float inv = rsqrtf(n0); c0 = two.x * inv; s0 = two.y * inv; }
        if (n1 > 0.f) { float inv = rsqrtf(n1); c1 = two.z * inv; s1 = two.w * inv; }
        int kb = tt >> 4;
        int off = (tt & 15) * 2;
        ushort* chunk = ztb + ((size_t)kb << 13) + cc * 32 + off;
        *(ushort2*)chunk          = make_ushort2(f2bf(c0), f2bf(c1));   // cos plane
        *(ushort2*)(chunk + 4096) = make_ushort2(f2bf(s0), f2bf(s1));   // sin plane
    }
}

// MFMA Gram partials. grid=(BATCH, NKCHUNK), block=256 (4 waves).
// Block computes full G[b][0:128][0:128] over its 512-k chunk (16 tiles of 32 k).
// Staging reads are fully contiguous 16 KB per tile (tiled zt layout).
__global__ __launch_bounds__(256, 2) void gram_kernel(const ushort* __restrict__ zt,
                                                      __half2* __restrict__ partial) {
    const int b = blockIdx.x, kc = blockIdx.y;
    const int tid = threadIdx.x;
    const int wave = tid >> 6;
    const int lane31 = tid & 31;
    const int half = (tid >> 5) & 1;

    __shared__ __align__(16) ushort sZ[2 * 128 * 40];   // C plane then S plane, stride 40

    f32x16 accRe[4], accIm[4];
#pragma unroll
    for (int v = 0; v < 4; ++v)
#pragma unroll
        for (int r = 0; r < 16; ++r) { accRe[v][r] = 0.f; accIm[v][r] = 0.f; }

    const ushort* cb0 = zt + (((size_t)b * 256 + kc * 16) << 13);

    const ushort* srcs[4];
    int ldst[4];
#pragma unroll
    for (int q = 0; q < 4; ++q) {
        int id = tid + (q << 8);                   // 0..1023 = plane*512 + row*4 + ck
        int plane = id >> 9;
        int rid = (id >> 2) & 127;
        int ck = id & 3;
        srcs[q] = cb0 + (size_t)id * 8;            // contiguous 16 KB chunk
        ldst[q] = plane * 5120 + rid * 40 + ck * 8;
    }

    uint4 pre[4];
#pragma unroll
    for (int q = 0; q < 4; ++q) pre[q] = *(const uint4*)srcs[q];

    for (int it = 0; it < 16; ++it) {
        __syncthreads();
#pragma unroll
        for (int q = 0; q < 4; ++q) *(uint4*)&sZ[ldst[q]] = pre[q];
        __syncthreads();
        if (it < 15) {
#pragma unroll
            for (int q = 0; q < 4; ++q) pre[q] = *(const uint4*)(srcs[q] + (it + 1) * 8192);
        }
#pragma unroll
        for (int kb = 0; kb < 32; kb += 16) {
            const int aoff = (wave * 32 + lane31) * 40 + kb + half * 8;
            bf16x8 aC = *(const bf16x8*)&sZ[aoff];
            bf16x8 aS = *(const bf16x8*)&sZ[5120 + aoff];
            bf16x8 aCn;
#pragma unroll
            for (int r = 0; r < 8; ++r) aCn[r] = (short)(aC[r] ^ (short)0x8000);
#pragma unroll
            for (int v = 0; v < 4; ++v) {
                const int boff = (v * 32 + lane31) * 40 + kb + half * 8;
                bf16x8 bC = *(const bf16x8*)&sZ[boff];
                bf16x8 bS = *(const bf16x8*)&sZ[5120 + boff];
                accRe[v] = __builtin_amdgcn_mfma_f32_32x32x16_bf16(aC,  bC, accRe[v], 0, 0, 0);
                accRe[v] = __builtin_amdgcn_mfma_f32_32x32x16_bf16(aS,  bS, accRe[v], 0, 0, 0);
                accIm[v] = __builtin_amdgcn_mfma_f32_32x32x16_bf16(aS,  bC, accIm[v], 0, 0, 0);
                accIm[v] = __builtin_amdgcn_mfma_f32_32x32x16_bf16(aCn, bS, accIm[v], 0, 0, 0);
            }
        }
    }

    // C/D layout (verified m74/m101): col=lane&31, row=(reg&3)+8*(reg>>2)+4*(lane>>5)
    __half2* pb = partial + ((size_t)(kc * BATCH + b) << 14);
#pragma unroll
    for (int v = 0; v < 4; ++v)
#pragma unroll
        for (int r = 0; r < 16; ++r) {
            int rrow = (r & 3) + 8 * (r >> 2) + 4 * half;
            int i = wave * 32 + rrow;
            int j = v * 32 + lane31;
            pb[i * CHN + j] = __floats2half2_rn(accRe[v][r], accIm[v][r]);
        }
}

__global__ __launch_bounds__(256) void reduce_kernel(const __half2* __restrict__ partial,
                                                     float* __restrict__ out) {
    const size_t i = (size_t)blockIdx.x * 256 + threadIdx.x;
    const size_t n = (size_t)BATCH * CHN * CHN;
    if (i >= n) return;
    float re = 0.0f, im = 0.0f;
#pragma unroll
    for (int c = 0; c < NKCHUNK; ++c) {
        float2 p = __half22float2(partial[(size_t)c * n + i]);
        re += p.x;
        im += p.y;
    }
    out[i] = sqrtf(re * re + im * im) * (1.0f / (float)T_LEN);
}

extern "C" void kernel_launch(void* const* d_in, const int* in_sizes, int n_in,
                              void* d_out, int out_size, void* d_ws, size_t ws_size,
                              hipStream_t stream) {
    const float* x = (const float*)d_in[0];
    float* out = (float*)d_out;

    ushort* zt = (ushort*)d_ws;                                          // 67.1 MB tiled z
    const size_t zt_elems = (size_t)BATCH * 256 * 8192;                  // b * kb * (2*128*32)
    __half2* partial = (__half2*)((char*)d_ws + zt_elems * sizeof(ushort)); // +16.78 MB

    fft_analytic_kernel<<<BATCH * CHN, 512, 0, stream>>>(x, zt);

    dim3 g2(BATCH, NKCHUNK);
    gram_kernel<<<g2, 256, 0, stream>>>(zt, partial);

    const int n_out = BATCH * CHN * CHN;
    reduce_kernel<<<(n_out + 255) / 256, 256, 0, stream>>>(partial, out);
}

// Round 5
// 333.111 us; speedup vs baseline: 1.0261x; 1.0261x over previous
//
#include <hip/hip_runtime.h>
#include <hip/hip_fp16.h>
#include <math.h>

#define T_LEN 8192
#define CHN 128
#define BATCH 16
#define NKCHUNK 16   // k-chunk = 512 = 8 tiles of 64

typedef short bf16x8 __attribute__((ext_vector_type(8)));
typedef float f32x16 __attribute__((ext_vector_type(16)));

#define SIN8 0.3826834323650898f
#define COS8 0.9238795325112868f
#define SROW 72          // LDS row stride (ushorts) = 144 B, 16B-aligned
#define SPLANE (128 * SROW)

__device__ __forceinline__ ushort f2bf(float f) {
    unsigned u = __float_as_uint(f);
    unsigned r = (u + 0x7fffu + ((u >> 16) & 1u)) >> 16;
    return (ushort)r;
}

__device__ __forceinline__ float2 cadd(float2 a, float2 b) { return make_float2(a.x + b.x, a.y + b.y); }
__device__ __forceinline__ float2 csub(float2 a, float2 b) { return make_float2(a.x - b.x, a.y - b.y); }
__device__ __forceinline__ float2 cmul(float2 a, float2 b) {
    return make_float2(a.x * b.x - a.y * b.y, a.x * b.y + a.y * b.x);
}

__device__ __forceinline__ void r4f(float2 x0, float2 x1, float2 x2, float2 x3,
                                    float2 wa, float2 wb, float2 wc,
                                    float2& y0, float2& y1, float2& y2, float2& y3) {
    float2 t0 = cadd(x0, x2), t1 = csub(x0, x2);
    float2 t2 = cadd(x1, x3), t3 = csub(x1, x3);
    y0 = cadd(t0, t2);
    y1 = cmul(csub(t0, t2), wb);
    y2 = cmul(make_float2(t1.x + t3.y, t1.y - t3.x), wa);
    y3 = cmul(make_float2(t1.x - t3.y, t1.y + t3.x), wc);
}

__device__ __forceinline__ void r4i(float2 x0, float2 x1, float2 x2, float2 x3,
                                    float2 wa, float2 wb, float2 wc,
                                    float2& y0, float2& y1, float2& y2, float2& y3) {
    float2 a1 = cmul(x1, wb);
    float2 a2 = cmul(x2, wa);
    float2 a3 = cmul(x3, wc);
    float2 u0 = cadd(x0, a1), u1 = csub(x0, a1);
    float2 p = cadd(a2, a3);
    float2 m = make_float2(-(a2.y - a3.y), a2.x - a3.x);
    y0 = cadd(u0, p); y2 = csub(u0, p);
    y1 = cadd(u1, m); y3 = csub(u1, m);
}

__device__ __forceinline__ void r8f(const float2* x, float sn, float cs, float2* y) {
    const float r22 = 0.70710678118654752f;
    float2 w1 = make_float2(cs, sn);
    float2 w2 = make_float2(cs * cs - sn * sn, 2.f * cs * sn);
    float2 w4 = cmul(w2, w2);
    float2 w6 = cmul(w4, w2);
    float2 u0 = cadd(x[0], x[4]), u1 = cadd(x[1], x[5]), u2 = cadd(x[2], x[6]), u3 = cadd(x[3], x[7]);
    float2 e0 = cmul(csub(x[0], x[4]), w1);
    float2 e1 = cmul(csub(x[1], x[5]), w1);
    float2 e2 = cmul(csub(x[2], x[6]), w1);
    float2 e3 = cmul(csub(x[3], x[7]), w1);
    float2 v0 = e0;
    float2 v1 = make_float2(r22 * (e1.x + e1.y), r22 * (e1.y - e1.x));
    float2 v2 = make_float2(e2.y, -e2.x);
    float2 v3 = make_float2(r22 * (e3.y - e3.x), -r22 * (e3.x + e3.y));
    r4f(u0, u1, u2, u3, w2, w4, w6, y[0], y[1], y[2], y[3]);
    r4f(v0, v1, v2, v3, w2, w4, w6, y[4], y[5], y[6], y[7]);
}

__device__ __forceinline__ void r8i(const float2* x, float sn, float cs, float2* y) {
    const float r22 = 0.70710678118654752f;
    float2 w1 = make_float2(cs, sn);
    float2 w2 = make_float2(cs * cs - sn * sn, 2.f * cs * sn);
    float2 w4 = cmul(w2, w2);
    float2 w6 = cmul(w4, w2);
    float2 g0, g1, g2, g3, g4, g5, g6, g7;
    r4i(x[0], x[1], x[2], x[3], w2, w4, w6, g0, g1, g2, g3);
    r4i(x[4], x[5], x[6], x[7], w2, w4, w6, g4, g5, g6, g7);
    float2 t0 = cmul(g4, w1);
    float2 e1 = cmul(g5, w1);
    float2 e2 = cmul(g6, w1);
    float2 e3 = cmul(g7, w1);
    float2 t1 = make_float2(r22 * (e1.x - e1.y), r22 * (e1.x + e1.y));
    float2 t2 = make_float2(-e2.y, e2.x);
    float2 t3 = make_float2(-r22 * (e3.x + e3.y), r22 * (e3.x - e3.y));
    y[0] = cadd(g0, t0); y[4] = csub(g0, t0);
    y[1] = cadd(g1, t1); y[5] = csub(g1, t1);
    y[2] = cadd(g2, t2); y[6] = csub(g2, t2);
    y[3] = cadd(g3, t3); y[7] = csub(g3, t3);
}

// One block per (b,c) row. 3 LDS radix-8 passes, register-local middle
// (dist 8,4,2 + mask-fused dist 1 + inv 2,4,8), 3 inverse LDS passes,
// normalize, store bf16 cos/sin into 64-wide tiled layout:
// zt[b][kb=k/64][plane][row(128)][k%64] -> row strip = 128 B full line,
// block-private (no partial-line RMW: R4's 246 MB WRITE_SIZE regression).
__global__ __launch_bounds__(512, 4) void fft_analytic_kernel(const float* __restrict__ x,
                                                              ushort* __restrict__ zt) {
    __shared__ __align__(16) float2 buf[T_LEN];   // 64 KiB
    const int tid = threadIdx.x;
    const int row = blockIdx.x;
    const float* xr = x + ((size_t)row << 13);

    for (int s = 0; s < 4; ++s) {
        int idx = tid + (s << 9);
        float4 v = *(const float4*)(xr + idx * 4);
        *(float4*)&buf[idx * 4]     = make_float4(v.x, 0.f, v.y, 0.f);
        *(float4*)&buf[idx * 4 + 2] = make_float4(v.z, 0.f, v.w, 0.f);
    }
    __syncthreads();

    for (int pq = 0; pq < 3; ++pq) {
        const int Q = 1024 >> (3 * pq);           // 1024,128,16
        const float astep = -(float)M_PI / (float)(4 * Q);
        for (int s = 0; s < 2; ++s) {
            const int g = tid + (s << 9);
            const int j = g & (Q - 1);
            const int i = ((g & ~(Q - 1)) << 3) | j;
            float2 xx[8], yy[8];
#pragma unroll
            for (int c = 0; c < 8; ++c) xx[c] = buf[i + c * Q];
            float sn, cs;
            __sincosf(astep * (float)j, &sn, &cs);
            r8f(xx, sn, cs, yy);
#pragma unroll
            for (int c = 0; c < 8; ++c) buf[i + c * Q] = yy[c];
        }
        __syncthreads();
    }

    // register-local middle: thread owns elements [16*tid, 16*tid+16)
    {
        float2 v[16];
        float4* bb = (float4*)buf;
#pragma unroll
        for (int p = 0; p < 8; ++p) {             // lane-staggered, conflict-free
            int pp = (p + tid) & 7;
            float4 f = bb[8 * tid + pp];
            v[2 * pp]     = make_float2(f.x, f.y);
            v[2 * pp + 1] = make_float2(f.z, f.w);
        }
        float2 xe[8], xo[8], E[8], O[8], t[8];
#pragma unroll
        for (int c = 0; c < 8; ++c) { xe[c] = v[2 * c]; xo[c] = v[2 * c + 1]; }
        r8f(xe, 0.f, 1.f, E);
        r8f(xo, -SIN8, COS8, O);
#pragma unroll
        for (int c = 0; c < 8; ++c) t[c] = cadd(E[c], O[c]);   // dist-1 + mask fuse
        r8i(t, 0.f, 1.f, xe);
        r8i(t, SIN8, COS8, xo);
#pragma unroll
        for (int c = 0; c < 8; ++c) { v[2 * c] = xe[c]; v[2 * c + 1] = xo[c]; }
#pragma unroll
        for (int p = 0; p < 8; ++p) {
            int pp = (p + tid) & 7;
            bb[8 * tid + pp] = make_float4(v[2 * pp].x, v[2 * pp].y,
                                           v[2 * pp + 1].x, v[2 * pp + 1].y);
        }
    }
    __syncthreads();

    for (int pq = 0; pq < 3; ++pq) {
        const int Q = 16 << (3 * pq);             // 16,128,1024
        const float astep = (float)M_PI / (float)(4 * Q);
        for (int s = 0; s < 2; ++s) {
            const int g = tid + (s << 9);
            const int j = g & (Q - 1);
            const int i = ((g & ~(Q - 1)) << 3) | j;
            float2 xx[8], yy[8];
#pragma unroll
            for (int c = 0; c < 8; ++c) xx[c] = buf[i + c * Q];
            float sn, cs;
            __sincosf(astep * (float)j, &sn, &cs);
            r8i(xx, sn, cs, yy);
#pragma unroll
            for (int c = 0; c < 8; ++c) buf[i + c * Q] = yy[c];
        }
        __syncthreads();
    }

    // normalize; store. chunk = 2 planes * 128 rows * 64 k = 16384 ushorts.
    const int bb_ = row >> 7, cc = row & 127;
    ushort* ztb = zt + ((size_t)bb_ << 21);       // b * 128 chunks * 16384
    for (int s = 0; s < 8; ++s) {
        int tt = tid + (s << 9);                  // handles k = 2tt, 2tt+1
        float4 two = *(const float4*)&buf[tt * 2];
        float n0 = two.x * two.x + two.y * two.y;
        float n1 = two.z * two.z + two.w * two.w;
        float c0 = 1.f, s0 = 0.f, c1 = 1.f, s1 = 0.f;
        if (n0 > 0.f) { float inv = rsqrtf(n0); c0 = two.x * inv; s0 = two.y * inv; }
        if (n1 > 0.f) { float inv = rsqrtf(n1); c1 = two.z * inv; s1 = two.w * inv; }
        int kb = tt >> 5;                         // chunk index (k/64)
        int off = (tt & 31) * 2;                  // k%64
        ushort* chunk = ztb + ((size_t)kb << 14) + cc * 64 + off;
        *(ushort2*)chunk          = make_ushort2(f2bf(c0), f2bf(c1));   // cos plane
        *(ushort2*)(chunk + 8192) = make_ushort2(f2bf(s0), f2bf(s1));   // sin plane
    }
}

// MFMA Gram partials. grid=(BATCH, NKCHUNK), block=512 (8 waves, 2/SIMD).
// Wave (wr=w&3, wcol=w>>2) computes rows wr*32..+32, cols wcol*64..+64.
// Staging: 8 iters of one contiguous 32-KB chunk (2 planes * 128 rows * 64 k).
__global__ __launch_bounds__(512, 2) void gram_kernel(const ushort* __restrict__ zt,
                                                      __half2* __restrict__ partial) {
    const int b = blockIdx.x, kc = blockIdx.y;
    const int tid = threadIdx.x;
    const int wave = tid >> 6;
    const int wr = wave & 3, wcol = wave >> 2;
    const int lane31 = tid & 31;
    const int half = (tid >> 5) & 1;

    __shared__ __align__(16) ushort sZ[2 * SPLANE];

    f32x16 accRe[2], accIm[2];
#pragma unroll
    for (int v = 0; v < 2; ++v)
#pragma unroll
        for (int r = 0; r < 16; ++r) { accRe[v][r] = 0.f; accIm[v][r] = 0.f; }

    const ushort* cb0 = zt + ((size_t)b << 21) + ((size_t)kc << 17);

    const ushort* srcs[4];
    int ldst[4];
#pragma unroll
    for (int q = 0; q < 4; ++q) {
        int id = tid + (q << 9);                   // 0..2047 over one 32-KB chunk
        int plane = id >> 10;
        int rid = (id >> 3) & 127;
        int ck = id & 7;
        srcs[q] = cb0 + (size_t)id * 8;            // fully contiguous
        ldst[q] = plane * SPLANE + rid * SROW + ck * 8;
    }

    uint4 pre[4];
#pragma unroll
    for (int q = 0; q < 4; ++q) pre[q] = *(const uint4*)srcs[q];

    for (int it = 0; it < 8; ++it) {
        __syncthreads();
#pragma unroll
        for (int q = 0; q < 4; ++q) *(uint4*)&sZ[ldst[q]] = pre[q];
        __syncthreads();
        if (it < 7) {
#pragma unroll
            for (int q = 0; q < 4; ++q) pre[q] = *(const uint4*)(srcs[q] + (it + 1) * 16384);
        }
#pragma unroll
        for (int kb = 0; kb < 64; kb += 16) {
            const int aoff = (wr * 32 + lane31) * SROW + kb + half * 8;
            bf16x8 aC = *(const bf16x8*)&sZ[aoff];
            bf16x8 aS = *(const bf16x8*)&sZ[SPLANE + aoff];
            bf16x8 aCn;
#pragma unroll
            for (int r = 0; r < 8; ++r) aCn[r] = (short)(aC[r] ^ (short)0x8000);
            bf16x8 bC[2], bS[2];
#pragma unroll
            for (int v = 0; v < 2; ++v) {
                const int boff = (wcol * 64 + v * 32 + lane31) * SROW + kb + half * 8;
                bC[v] = *(const bf16x8*)&sZ[boff];
                bS[v] = *(const bf16x8*)&sZ[SPLANE + boff];
            }
            // interleave so same-acc MFMAs are 4 apart (RAW spacing)
            accRe[0] = __builtin_amdgcn_mfma_f32_32x32x16_bf16(aC,  bC[0], accRe[0], 0, 0, 0);
            accRe[1] = __builtin_amdgcn_mfma_f32_32x32x16_bf16(aC,  bC[1], accRe[1], 0, 0, 0);
            accIm[0] = __builtin_amdgcn_mfma_f32_32x32x16_bf16(aS,  bC[0], accIm[0], 0, 0, 0);
            accIm[1] = __builtin_amdgcn_mfma_f32_32x32x16_bf16(aS,  bC[1], accIm[1], 0, 0, 0);
            accRe[0] = __builtin_amdgcn_mfma_f32_32x32x16_bf16(aS,  bS[0], accRe[0], 0, 0, 0);
            accRe[1] = __builtin_amdgcn_mfma_f32_32x32x16_bf16(aS,  bS[1], accRe[1], 0, 0, 0);
            accIm[0] = __builtin_amdgcn_mfma_f32_32x32x16_bf16(aCn, bS[0], accIm[0], 0, 0, 0);
            accIm[1] = __builtin_amdgcn_mfma_f32_32x32x16_bf16(aCn, bS[1], accIm[1], 0, 0, 0);
        }
    }

    // C/D layout (verified m74/m101): col=lane&31, row=(reg&3)+8*(reg>>2)+4*(lane>>5)
    __half2* pb = partial + ((size_t)(kc * BATCH + b) << 14);
#pragma unroll
    for (int v = 0; v < 2; ++v)
#pragma unroll
        for (int r = 0; r < 16; ++r) {
            int rrow = (r & 3) + 8 * (r >> 2) + 4 * half;
            int i = wr * 32 + rrow;
            int j = wcol * 64 + v * 32 + lane31;
            pb[i * CHN + j] = __floats2half2_rn(accRe[v][r], accIm[v][r]);
        }
}

__global__ __launch_bounds__(256) void reduce_kernel(const __half2* __restrict__ partial,
                                                     float* __restrict__ out) {
    const size_t i = (size_t)blockIdx.x * 256 + threadIdx.x;
    const size_t n = (size_t)BATCH * CHN * CHN;
    if (i >= n) return;
    float re = 0.0f, im = 0.0f;
#pragma unroll
    for (int c = 0; c < NKCHUNK; ++c) {
        float2 p = __half22float2(partial[(size_t)c * n + i]);
        re += p.x;
        im += p.y;
    }
    out[i] = sqrtf(re * re + im * im) * (1.0f / (float)T_LEN);
}

extern "C" void kernel_launch(void* const* d_in, const int* in_sizes, int n_in,
                              void* d_out, int out_size, void* d_ws, size_t ws_size,
                              hipStream_t stream) {
    const float* x = (const float*)d_in[0];
    float* out = (float*)d_out;

    ushort* zt = (ushort*)d_ws;                                          // 67.1 MB tiled z
    const size_t zt_elems = (size_t)BATCH * 128 * 16384;
    __half2* partial = (__half2*)((char*)d_ws + zt_elems * sizeof(ushort)); // +16.78 MB

    fft_analytic_kernel<<<BATCH * CHN, 512, 0, stream>>>(x, zt);

    dim3 g2(BATCH, NKCHUNK);
    gram_kernel<<<g2, 512, 0, stream>>>(zt, partial);

    const int n_out = BATCH * CHN * CHN;
    reduce_kernel<<<(n_out + 255) / 256, 256, 0, stream>>>(partial, out);
}

// Round 6
// 332.771 us; speedup vs baseline: 1.0271x; 1.0010x over previous
//
#include <hip/hip_runtime.h>
#include <hip/hip_fp16.h>
#include <math.h>

#define T_LEN 8192
#define CHN 128
#define BATCH 16
#define NKCHUNK 16   // k-chunk = 512 = 8 tiles of 64

typedef short bf16x8 __attribute__((ext_vector_type(8)));
typedef float f32x16 __attribute__((ext_vector_type(16)));

#define SIN8 0.3826834323650898f
#define COS8 0.9238795325112868f
#define SROW 72          // LDS row stride (ushorts) = 144 B, 16B-aligned
#define SPLANE (128 * SROW)

__device__ __forceinline__ ushort f2bf(float f) {
    unsigned u = __float_as_uint(f);
    unsigned r = (u + 0x7fffu + ((u >> 16) & 1u)) >> 16;
    return (ushort)r;
}

__device__ __forceinline__ float2 cadd(float2 a, float2 b) { return make_float2(a.x + b.x, a.y + b.y); }
__device__ __forceinline__ float2 csub(float2 a, float2 b) { return make_float2(a.x - b.x, a.y - b.y); }
__device__ __forceinline__ float2 cmul(float2 a, float2 b) {
    return make_float2(a.x * b.x - a.y * b.y, a.x * b.y + a.y * b.x);
}

__device__ __forceinline__ void r4f(float2 x0, float2 x1, float2 x2, float2 x3,
                                    float2 wa, float2 wb, float2 wc,
                                    float2& y0, float2& y1, float2& y2, float2& y3) {
    float2 t0 = cadd(x0, x2), t1 = csub(x0, x2);
    float2 t2 = cadd(x1, x3), t3 = csub(x1, x3);
    y0 = cadd(t0, t2);
    y1 = cmul(csub(t0, t2), wb);
    y2 = cmul(make_float2(t1.x + t3.y, t1.y - t3.x), wa);
    y3 = cmul(make_float2(t1.x - t3.y, t1.y + t3.x), wc);
}

__device__ __forceinline__ void r4i(float2 x0, float2 x1, float2 x2, float2 x3,
                                    float2 wa, float2 wb, float2 wc,
                                    float2& y0, float2& y1, float2& y2, float2& y3) {
    float2 a1 = cmul(x1, wb);
    float2 a2 = cmul(x2, wa);
    float2 a3 = cmul(x3, wc);
    float2 u0 = cadd(x0, a1), u1 = csub(x0, a1);
    float2 p = cadd(a2, a3);
    float2 m = make_float2(-(a2.y - a3.y), a2.x - a3.x);
    y0 = cadd(u0, p); y2 = csub(u0, p);
    y1 = cadd(u1, m); y3 = csub(u1, m);
}

__device__ __forceinline__ void r8f(const float2* x, float sn, float cs, float2* y) {
    const float r22 = 0.70710678118654752f;
    float2 w1 = make_float2(cs, sn);
    float2 w2 = make_float2(cs * cs - sn * sn, 2.f * cs * sn);
    float2 w4 = cmul(w2, w2);
    float2 w6 = cmul(w4, w2);
    float2 u0 = cadd(x[0], x[4]), u1 = cadd(x[1], x[5]), u2 = cadd(x[2], x[6]), u3 = cadd(x[3], x[7]);
    float2 e0 = cmul(csub(x[0], x[4]), w1);
    float2 e1 = cmul(csub(x[1], x[5]), w1);
    float2 e2 = cmul(csub(x[2], x[6]), w1);
    float2 e3 = cmul(csub(x[3], x[7]), w1);
    float2 v0 = e0;
    float2 v1 = make_float2(r22 * (e1.x + e1.y), r22 * (e1.y - e1.x));
    float2 v2 = make_float2(e2.y, -e2.x);
    float2 v3 = make_float2(r22 * (e3.y - e3.x), -r22 * (e3.x + e3.y));
    r4f(u0, u1, u2, u3, w2, w4, w6, y[0], y[1], y[2], y[3]);
    r4f(v0, v1, v2, v3, w2, w4, w6, y[4], y[5], y[6], y[7]);
}

__device__ __forceinline__ void r8i(const float2* x, float sn, float cs, float2* y) {
    const float r22 = 0.70710678118654752f;
    float2 w1 = make_float2(cs, sn);
    float2 w2 = make_float2(cs * cs - sn * sn, 2.f * cs * sn);
    float2 w4 = cmul(w2, w2);
    float2 w6 = cmul(w4, w2);
    float2 g0, g1, g2, g3, g4, g5, g6, g7;
    r4i(x[0], x[1], x[2], x[3], w2, w4, w6, g0, g1, g2, g3);
    r4i(x[4], x[5], x[6], x[7], w2, w4, w6, g4, g5, g6, g7);
    float2 t0 = cmul(g4, w1);
    float2 e1 = cmul(g5, w1);
    float2 e2 = cmul(g6, w1);
    float2 e3 = cmul(g7, w1);
    float2 t1 = make_float2(r22 * (e1.x - e1.y), r22 * (e1.x + e1.y));
    float2 t2 = make_float2(-e2.y, e2.x);
    float2 t3 = make_float2(-r22 * (e3.x + e3.y), r22 * (e3.x - e3.y));
    y[0] = cadd(g0, t0); y[4] = csub(g0, t0);
    y[1] = cadd(g1, t1); y[5] = csub(g1, t1);
    y[2] = cadd(g2, t2); y[6] = csub(g2, t2);
    y[3] = cadd(g3, t3); y[7] = csub(g3, t3);
}

// One block per (b,c) row. Fused global-load + fwd radix-8 pass (Q=1024),
// 2 LDS fwd passes (Q=128,16), register-local middle (dist 8..1..8),
// 2 LDS inv passes (Q=16,128), fused final inv pass (Q=1024) + normalize +
// row-major CONTIGUOUS store (R3-clean: WRITE_SIZE == z bytes; scattered
// strip stores cost 3.5x HBM write amplification — R4/R5 post-mortem).
__global__ __launch_bounds__(512, 4) void fft_analytic_kernel(const float* __restrict__ x,
                                                              ushort* __restrict__ zc,
                                                              ushort* __restrict__ zs) {
    __shared__ __align__(16) float2 buf[T_LEN];   // 64 KiB
    const int tid = threadIdx.x;
    const int row = blockIdx.x;
    const float* xr = x + ((size_t)row << 13);

    // fwd pass Q=1024 fused with global load (x real; imag folds away)
    for (int s = 0; s < 2; ++s) {
        const int g = tid + (s << 9);
        float2 X[8], Y[8];
#pragma unroll
        for (int c = 0; c < 8; ++c) X[c] = make_float2(xr[g + (c << 10)], 0.f);
        float sn, cs;
        __sincosf(-(float)M_PI / 4096.f * (float)g, &sn, &cs);
        r8f(X, sn, cs, Y);
#pragma unroll
        for (int c = 0; c < 8; ++c) buf[g + (c << 10)] = Y[c];
    }
    __syncthreads();

    // fwd LDS passes Q=128,16 (radix-2 distances 512..16)
    for (int pq = 0; pq < 2; ++pq) {
        const int Q = 128 >> (3 * pq);
        const float astep = -(float)M_PI / (float)(4 * Q);
        for (int s = 0; s < 2; ++s) {
            const int g = tid + (s << 9);
            const int j = g & (Q - 1);
            const int i = ((g & ~(Q - 1)) << 3) | j;
            float2 xx[8], yy[8];
#pragma unroll
            for (int c = 0; c < 8; ++c) xx[c] = buf[i + c * Q];
            float sn, cs;
            __sincosf(astep * (float)j, &sn, &cs);
            r8f(xx, sn, cs, yy);
#pragma unroll
            for (int c = 0; c < 8; ++c) buf[i + c * Q] = yy[c];
        }
        __syncthreads();
    }

    // register-local middle: thread owns elements [16*tid, 16*tid+16)
    {
        float2 v[16];
        float4* bb = (float4*)buf;
#pragma unroll
        for (int p = 0; p < 8; ++p) {             // lane-staggered, conflict-free
            int pp = (p + tid) & 7;
            float4 f = bb[8 * tid + pp];
            v[2 * pp]     = make_float2(f.x, f.y);
            v[2 * pp + 1] = make_float2(f.z, f.w);
        }
        float2 xe[8], xo[8], E[8], O[8], t[8];
#pragma unroll
        for (int c = 0; c < 8; ++c) { xe[c] = v[2 * c]; xo[c] = v[2 * c + 1]; }
        r8f(xe, 0.f, 1.f, E);
        r8f(xo, -SIN8, COS8, O);
#pragma unroll
        for (int c = 0; c < 8; ++c) t[c] = cadd(E[c], O[c]);   // dist-1 + mask fuse
        r8i(t, 0.f, 1.f, xe);
        r8i(t, SIN8, COS8, xo);
#pragma unroll
        for (int c = 0; c < 8; ++c) { v[2 * c] = xe[c]; v[2 * c + 1] = xo[c]; }
#pragma unroll
        for (int p = 0; p < 8; ++p) {
            int pp = (p + tid) & 7;
            bb[8 * tid + pp] = make_float4(v[2 * pp].x, v[2 * pp].y,
                                           v[2 * pp + 1].x, v[2 * pp + 1].y);
        }
    }
    __syncthreads();

    // inv LDS passes Q=16,128 (radix-2 distances 16..512)
    for (int pq = 0; pq < 2; ++pq) {
        const int Q = 16 << (3 * pq);
        const float astep = (float)M_PI / (float)(4 * Q);
        for (int s = 0; s < 2; ++s) {
            const int g = tid + (s << 9);
            const int j = g & (Q - 1);
            const int i = ((g & ~(Q - 1)) << 3) | j;
            float2 xx[8], yy[8];
#pragma unroll
            for (int c = 0; c < 8; ++c) xx[c] = buf[i + c * Q];
            float sn, cs;
            __sincosf(astep * (float)j, &sn, &cs);
            r8i(xx, sn, cs, yy);
#pragma unroll
            for (int c = 0; c < 8; ++c) buf[i + c * Q] = yy[c];
        }
        __syncthreads();
    }

    // final inv pass Q=1024 fused with normalize + contiguous row-major store
    ushort* zcr = zc + ((size_t)row << 13);
    ushort* zsr = zs + ((size_t)row << 13);
    for (int s = 0; s < 2; ++s) {
        const int g = tid + (s << 9);
        float2 xx[8], yy[8];
#pragma unroll
        for (int c = 0; c < 8; ++c) xx[c] = buf[g + (c << 10)];
        float sn, cs;
        __sincosf((float)M_PI / 4096.f * (float)g, &sn, &cs);
        r8i(xx, sn, cs, yy);
#pragma unroll
        for (int c = 0; c < 8; ++c) {
            float2 vv = yy[c];
            float n2 = vv.x * vv.x + vv.y * vv.y;
            float cc = 1.f, ss = 0.f;
            if (n2 > 0.f) { float inv = rsqrtf(n2); cc = vv.x * inv; ss = vv.y * inv; }
            zcr[g + (c << 10)] = f2bf(cc);
            zsr[g + (c << 10)] = f2bf(ss);
        }
    }
}

// MFMA Gram partials. grid=(BATCH, NKCHUNK), block=512 (8 waves, 2/SIMD).
// Wave (wr=w&3, wcol=w>>2) computes rows wr*32..+32, cols wcol*64..+64.
// Staging from row-major planes (16-KB row stride — proven non-bottleneck R3/R5).
__global__ __launch_bounds__(512, 2) void gram_kernel(const ushort* __restrict__ zc,
                                                      const ushort* __restrict__ zs,
                                                      __half2* __restrict__ partial) {
    const int b = blockIdx.x, kc = blockIdx.y;
    const int tid = threadIdx.x;
    const int wave = tid >> 6;
    const int wr = wave & 3, wcol = wave >> 2;
    const int lane31 = tid & 31;
    const int half = (tid >> 5) & 1;

    __shared__ __align__(16) ushort sZ[2 * SPLANE];

    f32x16 accRe[2], accIm[2];
#pragma unroll
    for (int v = 0; v < 2; ++v)
#pragma unroll
        for (int r = 0; r < 16; ++r) { accRe[v][r] = 0.f; accIm[v][r] = 0.f; }

    const size_t base = ((size_t)b * CHN) << 13;
    const int k0 = kc << 9;   // *512

    const ushort* srcs[4];
    int ldst[4];
#pragma unroll
    for (int q = 0; q < 4; ++q) {
        int id = tid + (q << 9);                   // 0..2047 = plane*1024 + rid*8 + ck
        int plane = id >> 10;
        int rid = (id >> 3) & 127;
        int ck = id & 7;
        srcs[q] = (plane ? zs : zc) + base + ((size_t)rid << 13) + (size_t)(k0 + ck * 8);
        ldst[q] = plane * SPLANE + rid * SROW + ck * 8;
    }

    uint4 pre[4];
#pragma unroll
    for (int q = 0; q < 4; ++q) pre[q] = *(const uint4*)srcs[q];

    for (int it = 0; it < 8; ++it) {
        __syncthreads();
#pragma unroll
        for (int q = 0; q < 4; ++q) *(uint4*)&sZ[ldst[q]] = pre[q];
        __syncthreads();
        if (it < 7) {
#pragma unroll
            for (int q = 0; q < 4; ++q) pre[q] = *(const uint4*)(srcs[q] + (it + 1) * 64);
        }
#pragma unroll
        for (int kb = 0; kb < 64; kb += 16) {
            const int aoff = (wr * 32 + lane31) * SROW + kb + half * 8;
            bf16x8 aC = *(const bf16x8*)&sZ[aoff];
            bf16x8 aS = *(const bf16x8*)&sZ[SPLANE + aoff];
            bf16x8 aCn;
#pragma unroll
            for (int r = 0; r < 8; ++r) aCn[r] = (short)(aC[r] ^ (short)0x8000);
            bf16x8 bC[2], bS[2];
#pragma unroll
            for (int v = 0; v < 2; ++v) {
                const int boff = (wcol * 64 + v * 32 + lane31) * SROW + kb + half * 8;
                bC[v] = *(const bf16x8*)&sZ[boff];
                bS[v] = *(const bf16x8*)&sZ[SPLANE + boff];
            }
            accRe[0] = __builtin_amdgcn_mfma_f32_32x32x16_bf16(aC,  bC[0], accRe[0], 0, 0, 0);
            accRe[1] = __builtin_amdgcn_mfma_f32_32x32x16_bf16(aC,  bC[1], accRe[1], 0, 0, 0);
            accIm[0] = __builtin_amdgcn_mfma_f32_32x32x16_bf16(aS,  bC[0], accIm[0], 0, 0, 0);
            accIm[1] = __builtin_amdgcn_mfma_f32_32x32x16_bf16(aS,  bC[1], accIm[1], 0, 0, 0);
            accRe[0] = __builtin_amdgcn_mfma_f32_32x32x16_bf16(aS,  bS[0], accRe[0], 0, 0, 0);
            accRe[1] = __builtin_amdgcn_mfma_f32_32x32x16_bf16(aS,  bS[1], accRe[1], 0, 0, 0);
            accIm[0] = __builtin_amdgcn_mfma_f32_32x32x16_bf16(aCn, bS[0], accIm[0], 0, 0, 0);
            accIm[1] = __builtin_amdgcn_mfma_f32_32x32x16_bf16(aCn, bS[1], accIm[1], 0, 0, 0);
        }
    }

    // C/D layout (verified m74/m101): col=lane&31, row=(reg&3)+8*(reg>>2)+4*(lane>>5)
    __half2* pb = partial + ((size_t)(kc * BATCH + b) << 14);
#pragma unroll
    for (int v = 0; v < 2; ++v)
#pragma unroll
        for (int r = 0; r < 16; ++r) {
            int rrow = (r & 3) + 8 * (r >> 2) + 4 * half;
            int i = wr * 32 + rrow;
            int j = wcol * 64 + v * 32 + lane31;
            pb[i * CHN + j] = __floats2half2_rn(accRe[v][r], accIm[v][r]);
        }
}

__global__ __launch_bounds__(256) void reduce_kernel(const __half2* __restrict__ partial,
                                                     float* __restrict__ out) {
    const size_t i = (size_t)blockIdx.x * 256 + threadIdx.x;
    const size_t n = (size_t)BATCH * CHN * CHN;
    if (i >= n) return;
    float re = 0.0f, im = 0.0f;
#pragma unroll
    for (int c = 0; c < NKCHUNK; ++c) {
        float2 p = __half22float2(partial[(size_t)c * n + i]);
        re += p.x;
        im += p.y;
    }
    out[i] = sqrtf(re * re + im * im) * (1.0f / (float)T_LEN);
}

extern "C" void kernel_launch(void* const* d_in, const int* in_sizes, int n_in,
                              void* d_out, int out_size, void* d_ws, size_t ws_size,
                              hipStream_t stream) {
    const float* x = (const float*)d_in[0];
    float* out = (float*)d_out;

    const size_t plane_elems = (size_t)BATCH * CHN * T_LEN;                 // 16.8M
    ushort* zc = (ushort*)d_ws;                                             // 33.55 MB
    ushort* zs = zc + plane_elems;                                          // +33.55 MB
    __half2* partial = (__half2*)((char*)d_ws + 2 * plane_elems * sizeof(ushort)); // +16.78 MB

    fft_analytic_kernel<<<BATCH * CHN, 512, 0, stream>>>(x, zc, zs);

    dim3 g2(BATCH, NKCHUNK);
    gram_kernel<<<g2, 512, 0, stream>>>(zc, zs, partial);

    const int n_out = BATCH * CHN * CHN;
    reduce_kernel<<<(n_out + 255) / 256, 256, 0, stream>>>(partial, out);
}

// Round 7
// 216.495 us; speedup vs baseline: 1.5788x; 1.5371x over previous
//
#include <hip/hip_runtime.h>
#include <hip/hip_fp16.h>
#include <math.h>

#define T_LEN 8192
#define CHN 128
#define BATCH 16
#define NKCHUNK 16   // k-chunk = 512 = 8 tiles of 64

typedef short bf16x8 __attribute__((ext_vector_type(8)));
typedef float f32x16 __attribute__((ext_vector_type(16)));

#define SIN8 0.3826834323650898f
#define COS8 0.9238795325112868f
#define SROW 72          // LDS row stride (ushorts) = 144 B, 16B-aligned
#define SPLANE (128 * SROW)

__device__ __forceinline__ ushort f2bf(float f) {
    unsigned u = __float_as_uint(f);
    unsigned r = (u + 0x7fffu + ((u >> 16) & 1u)) >> 16;
    return (ushort)r;
}

__device__ __forceinline__ float2 cadd(float2 a, float2 b) { return make_float2(a.x + b.x, a.y + b.y); }
__device__ __forceinline__ float2 csub(float2 a, float2 b) { return make_float2(a.x - b.x, a.y - b.y); }
__device__ __forceinline__ float2 cmul(float2 a, float2 b) {
    return make_float2(a.x * b.x - a.y * b.y, a.x * b.y + a.y * b.x);
}

__device__ __forceinline__ void r4f(float2 x0, float2 x1, float2 x2, float2 x3,
                                    float2 wa, float2 wb, float2 wc,
                                    float2& y0, float2& y1, float2& y2, float2& y3) {
    float2 t0 = cadd(x0, x2), t1 = csub(x0, x2);
    float2 t2 = cadd(x1, x3), t3 = csub(x1, x3);
    y0 = cadd(t0, t2);
    y1 = cmul(csub(t0, t2), wb);
    y2 = cmul(make_float2(t1.x + t3.y, t1.y - t3.x), wa);
    y3 = cmul(make_float2(t1.x - t3.y, t1.y + t3.x), wc);
}

__device__ __forceinline__ void r4i(float2 x0, float2 x1, float2 x2, float2 x3,
                                    float2 wa, float2 wb, float2 wc,
                                    float2& y0, float2& y1, float2& y2, float2& y3) {
    float2 a1 = cmul(x1, wb);
    float2 a2 = cmul(x2, wa);
    float2 a3 = cmul(x3, wc);
    float2 u0 = cadd(x0, a1), u1 = csub(x0, a1);
    float2 p = cadd(a2, a3);
    float2 m = make_float2(-(a2.y - a3.y), a2.x - a3.x);
    y0 = cadd(u0, p); y2 = csub(u0, p);
    y1 = cadd(u1, m); y3 = csub(u1, m);
}

__device__ __forceinline__ void r8f(const float2* x, float sn, float cs, float2* y) {
    const float r22 = 0.70710678118654752f;
    float2 w1 = make_float2(cs, sn);
    float2 w2 = make_float2(cs * cs - sn * sn, 2.f * cs * sn);
    float2 w4 = cmul(w2, w2);
    float2 w6 = cmul(w4, w2);
    float2 u0 = cadd(x[0], x[4]), u1 = cadd(x[1], x[5]), u2 = cadd(x[2], x[6]), u3 = cadd(x[3], x[7]);
    float2 e0 = cmul(csub(x[0], x[4]), w1);
    float2 e1 = cmul(csub(x[1], x[5]), w1);
    float2 e2 = cmul(csub(x[2], x[6]), w1);
    float2 e3 = cmul(csub(x[3], x[7]), w1);
    float2 v0 = e0;
    float2 v1 = make_float2(r22 * (e1.x + e1.y), r22 * (e1.y - e1.x));
    float2 v2 = make_float2(e2.y, -e2.x);
    float2 v3 = make_float2(r22 * (e3.y - e3.x), -r22 * (e3.x + e3.y));
    r4f(u0, u1, u2, u3, w2, w4, w6, y[0], y[1], y[2], y[3]);
    r4f(v0, v1, v2, v3, w2, w4, w6, y[4], y[5], y[6], y[7]);
}

__device__ __forceinline__ void r8i(const float2* x, float sn, float cs, float2* y) {
    const float r22 = 0.70710678118654752f;
    float2 w1 = make_float2(cs, sn);
    float2 w2 = make_float2(cs * cs - sn * sn, 2.f * cs * sn);
    float2 w4 = cmul(w2, w2);
    float2 w6 = cmul(w4, w2);
    float2 g0, g1, g2, g3, g4, g5, g6, g7;
    r4i(x[0], x[1], x[2], x[3], w2, w4, w6, g0, g1, g2, g3);
    r4i(x[4], x[5], x[6], x[7], w2, w4, w6, g4, g5, g6, g7);
    float2 t0 = cmul(g4, w1);
    float2 e1 = cmul(g5, w1);
    float2 e2 = cmul(g6, w1);
    float2 e3 = cmul(g7, w1);
    float2 t1 = make_float2(r22 * (e1.x - e1.y), r22 * (e1.x + e1.y));
    float2 t2 = make_float2(-e2.y, e2.x);
    float2 t3 = make_float2(-r22 * (e3.x + e3.y), r22 * (e3.x - e3.y));
    y[0] = cadd(g0, t0); y[4] = csub(g0, t0);
    y[1] = cadd(g1, t1); y[5] = csub(g1, t1);
    y[2] = cadd(g2, t2); y[6] = csub(g2, t2);
    y[3] = cadd(g3, t3); y[7] = csub(g3, t3);
}

// One block per (b,c) row. Fused global-load + fwd radix-8 (Q=1024), 2 LDS fwd
// passes, register-local middle (ALL indices compile-time: runtime-indexed
// local arrays go to scratch -> 166 MB of HBM spill traffic, the R4-R6 bug),
// 2 LDS inv passes, fused final inv pass + normalize + contiguous store.
__global__ __launch_bounds__(512, 4) void fft_analytic_kernel(const float* __restrict__ x,
                                                              ushort* __restrict__ zc,
                                                              ushort* __restrict__ zs) {
    __shared__ __align__(16) float2 buf[T_LEN];   // 64 KiB
    const int tid = threadIdx.x;
    const int row = blockIdx.x;
    const float* xr = x + ((size_t)row << 13);

    // fwd pass Q=1024 fused with global load (x real; imag folds away)
    for (int s = 0; s < 2; ++s) {
        const int g = tid + (s << 9);
        float2 X[8], Y[8];
#pragma unroll
        for (int c = 0; c < 8; ++c) X[c] = make_float2(xr[g + (c << 10)], 0.f);
        float sn, cs;
        __sincosf(-(float)M_PI / 4096.f * (float)g, &sn, &cs);
        r8f(X, sn, cs, Y);
#pragma unroll
        for (int c = 0; c < 8; ++c) buf[g + (c << 10)] = Y[c];
    }
    __syncthreads();

    // fwd LDS passes Q=128,16 (radix-2 distances 512..16)
    for (int pq = 0; pq < 2; ++pq) {
        const int Q = 128 >> (3 * pq);
        const float astep = -(float)M_PI / (float)(4 * Q);
        for (int s = 0; s < 2; ++s) {
            const int g = tid + (s << 9);
            const int j = g & (Q - 1);
            const int i = ((g & ~(Q - 1)) << 3) | j;
            float2 xx[8], yy[8];
#pragma unroll
            for (int c = 0; c < 8; ++c) xx[c] = buf[i + c * Q];
            float sn, cs;
            __sincosf(astep * (float)j, &sn, &cs);
            r8f(xx, sn, cs, yy);
#pragma unroll
            for (int c = 0; c < 8; ++c) buf[i + c * Q] = yy[c];
        }
        __syncthreads();
    }

    // register-local middle: thread owns elements [16*tid, 16*tid+16).
    // Direct compile-time indexing (b128 reads; bank aliasing accepted —
    // ~6 us aggregate vs ~140 us scratch round-trip of the staggered version).
    {
        float2 v[16];
        float4* bb = (float4*)buf;
#pragma unroll
        for (int p = 0; p < 8; ++p) {
            float4 f = bb[8 * tid + p];
            v[2 * p]     = make_float2(f.x, f.y);
            v[2 * p + 1] = make_float2(f.z, f.w);
        }
        float2 xe[8], xo[8], E[8], O[8], t[8];
#pragma unroll
        for (int c = 0; c < 8; ++c) { xe[c] = v[2 * c]; xo[c] = v[2 * c + 1]; }
        r8f(xe, 0.f, 1.f, E);
        r8f(xo, -SIN8, COS8, O);
#pragma unroll
        for (int c = 0; c < 8; ++c) t[c] = cadd(E[c], O[c]);   // dist-1 + mask fuse
        r8i(t, 0.f, 1.f, xe);
        r8i(t, SIN8, COS8, xo);
#pragma unroll
        for (int p = 0; p < 8; ++p)
            bb[8 * tid + p] = make_float4(xe[p].x, xe[p].y, xo[p].x, xo[p].y);
    }
    __syncthreads();

    // inv LDS passes Q=16,128 (radix-2 distances 16..512)
    for (int pq = 0; pq < 2; ++pq) {
        const int Q = 16 << (3 * pq);
        const float astep = (float)M_PI / (float)(4 * Q);
        for (int s = 0; s < 2; ++s) {
            const int g = tid + (s << 9);
            const int j = g & (Q - 1);
            const int i = ((g & ~(Q - 1)) << 3) | j;
            float2 xx[8], yy[8];
#pragma unroll
            for (int c = 0; c < 8; ++c) xx[c] = buf[i + c * Q];
            float sn, cs;
            __sincosf(astep * (float)j, &sn, &cs);
            r8i(xx, sn, cs, yy);
#pragma unroll
            for (int c = 0; c < 8; ++c) buf[i + c * Q] = yy[c];
        }
        __syncthreads();
    }

    // final inv pass Q=1024 fused with normalize + contiguous row-major store
    ushort* zcr = zc + ((size_t)row << 13);
    ushort* zsr = zs + ((size_t)row << 13);
    for (int s = 0; s < 2; ++s) {
        const int g = tid + (s << 9);
        float2 xx[8], yy[8];
#pragma unroll
        for (int c = 0; c < 8; ++c) xx[c] = buf[g + (c << 10)];
        float sn, cs;
        __sincosf((float)M_PI / 4096.f * (float)g, &sn, &cs);
        r8i(xx, sn, cs, yy);
#pragma unroll
        for (int c = 0; c < 8; ++c) {
            float2 vv = yy[c];
            float n2 = vv.x * vv.x + vv.y * vv.y;
            float cc = 1.f, ss = 0.f;
            if (n2 > 0.f) { float inv = rsqrtf(n2); cc = vv.x * inv; ss = vv.y * inv; }
            zcr[g + (c << 10)] = f2bf(cc);
            zsr[g + (c << 10)] = f2bf(ss);
        }
    }
}

// MFMA Gram partials. grid=(BATCH, NKCHUNK), block=512 (8 waves, 2/SIMD).
__global__ __launch_bounds__(512, 2) void gram_kernel(const ushort* __restrict__ zc,
                                                      const ushort* __restrict__ zs,
                                                      __half2* __restrict__ partial) {
    const int b = blockIdx.x, kc = blockIdx.y;
    const int tid = threadIdx.x;
    const int wave = tid >> 6;
    const int wr = wave & 3, wcol = wave >> 2;
    const int lane31 = tid & 31;
    const int half = (tid >> 5) & 1;

    __shared__ __align__(16) ushort sZ[2 * SPLANE];

    f32x16 accRe[2], accIm[2];
#pragma unroll
    for (int v = 0; v < 2; ++v)
#pragma unroll
        for (int r = 0; r < 16; ++r) { accRe[v][r] = 0.f; accIm[v][r] = 0.f; }

    const size_t base = ((size_t)b * CHN) << 13;
    const int k0 = kc << 9;   // *512

    const ushort* srcs[4];
    int ldst[4];
#pragma unroll
    for (int q = 0; q < 4; ++q) {
        int id = tid + (q << 9);                   // 0..2047 = plane*1024 + rid*8 + ck
        int plane = id >> 10;
        int rid = (id >> 3) & 127;
        int ck = id & 7;
        srcs[q] = (plane ? zs : zc) + base + ((size_t)rid << 13) + (size_t)(k0 + ck * 8);
        ldst[q] = plane * SPLANE + rid * SROW + ck * 8;
    }

    uint4 pre[4];
#pragma unroll
    for (int q = 0; q < 4; ++q) pre[q] = *(const uint4*)srcs[q];

    for (int it = 0; it < 8; ++it) {
        __syncthreads();
#pragma unroll
        for (int q = 0; q < 4; ++q) *(uint4*)&sZ[ldst[q]] = pre[q];
        __syncthreads();
        if (it < 7) {
#pragma unroll
            for (int q = 0; q < 4; ++q) pre[q] = *(const uint4*)(srcs[q] + (it + 1) * 64);
        }
#pragma unroll
        for (int kb = 0; kb < 64; kb += 16) {
            const int aoff = (wr * 32 + lane31) * SROW + kb + half * 8;
            bf16x8 aC = *(const bf16x8*)&sZ[aoff];
            bf16x8 aS = *(const bf16x8*)&sZ[SPLANE + aoff];
            bf16x8 aCn;
#pragma unroll
            for (int r = 0; r < 8; ++r) aCn[r] = (short)(aC[r] ^ (short)0x8000);
            bf16x8 bC[2], bS[2];
#pragma unroll
            for (int v = 0; v < 2; ++v) {
                const int boff = (wcol * 64 + v * 32 + lane31) * SROW + kb + half * 8;
                bC[v] = *(const bf16x8*)&sZ[boff];
                bS[v] = *(const bf16x8*)&sZ[SPLANE + boff];
            }
            accRe[0] = __builtin_amdgcn_mfma_f32_32x32x16_bf16(aC,  bC[0], accRe[0], 0, 0, 0);
            accRe[1] = __builtin_amdgcn_mfma_f32_32x32x16_bf16(aC,  bC[1], accRe[1], 0, 0, 0);
            accIm[0] = __builtin_amdgcn_mfma_f32_32x32x16_bf16(aS,  bC[0], accIm[0], 0, 0, 0);
            accIm[1] = __builtin_amdgcn_mfma_f32_32x32x16_bf16(aS,  bC[1], accIm[1], 0, 0, 0);
            accRe[0] = __builtin_amdgcn_mfma_f32_32x32x16_bf16(aS,  bS[0], accRe[0], 0, 0, 0);
            accRe[1] = __builtin_amdgcn_mfma_f32_32x32x16_bf16(aS,  bS[1], accRe[1], 0, 0, 0);
            accIm[0] = __builtin_amdgcn_mfma_f32_32x32x16_bf16(aCn, bS[0], accIm[0], 0, 0, 0);
            accIm[1] = __builtin_amdgcn_mfma_f32_32x32x16_bf16(aCn, bS[1], accIm[1], 0, 0, 0);
        }
    }

    // C/D layout (verified m74/m101): col=lane&31, row=(reg&3)+8*(reg>>2)+4*(lane>>5)
    __half2* pb = partial + ((size_t)(kc * BATCH + b) << 14);
#pragma unroll
    for (int v = 0; v < 2; ++v)
#pragma unroll
        for (int r = 0; r < 16; ++r) {
            int rrow = (r & 3) + 8 * (r >> 2) + 4 * half;
            int i = wr * 32 + rrow;
            int j = wcol * 64 + v * 32 + lane31;
            pb[i * CHN + j] = __floats2half2_rn(accRe[v][r], accIm[v][r]);
        }
}

__global__ __launch_bounds__(256) void reduce_kernel(const __half2* __restrict__ partial,
                                                     float* __restrict__ out) {
    const size_t i = (size_t)blockIdx.x * 256 + threadIdx.x;
    const size_t n = (size_t)BATCH * CHN * CHN;
    if (i >= n) return;
    float re = 0.0f, im = 0.0f;
#pragma unroll
    for (int c = 0; c < NKCHUNK; ++c) {
        float2 p = __half22float2(partial[(size_t)c * n + i]);
        re += p.x;
        im += p.y;
    }
    out[i] = sqrtf(re * re + im * im) * (1.0f / (float)T_LEN);
}

extern "C" void kernel_launch(void* const* d_in, const int* in_sizes, int n_in,
                              void* d_out, int out_size, void* d_ws, size_t ws_size,
                              hipStream_t stream) {
    const float* x = (const float*)d_in[0];
    float* out = (float*)d_out;

    const size_t plane_elems = (size_t)BATCH * CHN * T_LEN;                 // 16.8M
    ushort* zc = (ushort*)d_ws;                                             // 33.55 MB
    ushort* zs = zc + plane_elems;                                          // +33.55 MB
    __half2* partial = (__half2*)((char*)d_ws + 2 * plane_elems * sizeof(ushort)); // +16.78 MB

    fft_analytic_kernel<<<BATCH * CHN, 512, 0, stream>>>(x, zc, zs);

    dim3 g2(BATCH, NKCHUNK);
    gram_kernel<<<g2, 512, 0, stream>>>(zc, zs, partial);

    const int n_out = BATCH * CHN * CHN;
    reduce_kernel<<<(n_out + 255) / 256, 256, 0, stream>>>(partial, out);
}

// Round 8
// 177.641 us; speedup vs baseline: 1.9241x; 1.2187x over previous
//
#include <hip/hip_runtime.h>
#include <hip/hip_fp16.h>
#include <math.h>

#define T_LEN 8192
#define CHN 128
#define BATCH 16
#define NKCHUNK 16   // k-chunk = 512 = 8 tiles of 64

typedef short bf16x8 __attribute__((ext_vector_type(8)));
typedef float f32x16 __attribute__((ext_vector_type(16)));

#define SIN8 0.3826834323650898f
#define COS8 0.9238795325112868f
#define SROW 72          // LDS row stride (ushorts) = 144 B, 16B-aligned
#define SPLANE (128 * SROW)

__device__ __forceinline__ ushort f2bf(float f) {
    unsigned u = __float_as_uint(f);
    unsigned r = (u + 0x7fffu + ((u >> 16) & 1u)) >> 16;
    return (ushort)r;
}

__device__ __forceinline__ float2 cadd(float2 a, float2 b) { return make_float2(a.x + b.x, a.y + b.y); }
__device__ __forceinline__ float2 csub(float2 a, float2 b) { return make_float2(a.x - b.x, a.y - b.y); }
__device__ __forceinline__ float2 cmul(float2 a, float2 b) {
    return make_float2(a.x * b.x - a.y * b.y, a.x * b.y + a.y * b.x);
}

__device__ __forceinline__ void r4f(float2 x0, float2 x1, float2 x2, float2 x3,
                                    float2 wa, float2 wb, float2 wc,
                                    float2& y0, float2& y1, float2& y2, float2& y3) {
    float2 t0 = cadd(x0, x2), t1 = csub(x0, x2);
    float2 t2 = cadd(x1, x3), t3 = csub(x1, x3);
    y0 = cadd(t0, t2);
    y1 = cmul(csub(t0, t2), wb);
    y2 = cmul(make_float2(t1.x + t3.y, t1.y - t3.x), wa);
    y3 = cmul(make_float2(t1.x - t3.y, t1.y + t3.x), wc);
}

__device__ __forceinline__ void r4i(float2 x0, float2 x1, float2 x2, float2 x3,
                                    float2 wa, float2 wb, float2 wc,
                                    float2& y0, float2& y1, float2& y2, float2& y3) {
    float2 a1 = cmul(x1, wb);
    float2 a2 = cmul(x2, wa);
    float2 a3 = cmul(x3, wc);
    float2 u0 = cadd(x0, a1), u1 = csub(x0, a1);
    float2 p = cadd(a2, a3);
    float2 m = make_float2(-(a2.y - a3.y), a2.x - a3.x);
    y0 = cadd(u0, p); y2 = csub(u0, p);
    y1 = cadd(u1, m); y3 = csub(u1, m);
}

__device__ __forceinline__ void r8f(const float2* x, float sn, float cs, float2* y) {
    const float r22 = 0.70710678118654752f;
    float2 w1 = make_float2(cs, sn);
    float2 w2 = make_float2(cs * cs - sn * sn, 2.f * cs * sn);
    float2 w4 = cmul(w2, w2);
    float2 w6 = cmul(w4, w2);
    float2 u0 = cadd(x[0], x[4]), u1 = cadd(x[1], x[5]), u2 = cadd(x[2], x[6]), u3 = cadd(x[3], x[7]);
    float2 e0 = cmul(csub(x[0], x[4]), w1);
    float2 e1 = cmul(csub(x[1], x[5]), w1);
    float2 e2 = cmul(csub(x[2], x[6]), w1);
    float2 e3 = cmul(csub(x[3], x[7]), w1);
    float2 v0 = e0;
    float2 v1 = make_float2(r22 * (e1.x + e1.y), r22 * (e1.y - e1.x));
    float2 v2 = make_float2(e2.y, -e2.x);
    float2 v3 = make_float2(r22 * (e3.y - e3.x), -r22 * (e3.x + e3.y));
    r4f(u0, u1, u2, u3, w2, w4, w6, y[0], y[1], y[2], y[3]);
    r4f(v0, v1, v2, v3, w2, w4, w6, y[4], y[5], y[6], y[7]);
}

__device__ __forceinline__ void r8i(const float2* x, float sn, float cs, float2* y) {
    const float r22 = 0.70710678118654752f;
    float2 w1 = make_float2(cs, sn);
    float2 w2 = make_float2(cs * cs - sn * sn, 2.f * cs * sn);
    float2 w4 = cmul(w2, w2);
    float2 w6 = cmul(w4, w2);
    float2 g0, g1, g2, g3, g4, g5, g6, g7;
    r4i(x[0], x[1], x[2], x[3], w2, w4, w6, g0, g1, g2, g3);
    r4i(x[4], x[5], x[6], x[7], w2, w4, w6, g4, g5, g6, g7);
    float2 t0 = cmul(g4, w1);
    float2 e1 = cmul(g5, w1);
    float2 e2 = cmul(g6, w1);
    float2 e3 = cmul(g7, w1);
    float2 t1 = make_float2(r22 * (e1.x - e1.y), r22 * (e1.x + e1.y));
    float2 t2 = make_float2(-e2.y, e2.x);
    float2 t3 = make_float2(-r22 * (e3.x + e3.y), r22 * (e3.x - e3.y));
    y[0] = cadd(g0, t0); y[4] = csub(g0, t0);
    y[1] = cadd(g1, t1); y[5] = csub(g1, t1);
    y[2] = cadd(g2, t2); y[6] = csub(g2, t2);
    y[3] = cadd(g3, t3); y[7] = csub(g3, t3);
}

// One block per (b,c) row. Fused load+fwd radix-8 (Q=1024), fwd Q=128 pass,
// fwd Q=16 pass (plain reads, XOR-swizzled writes), register-local middle
// (swizzled slots: element-f4 F at slot F^(tid&7) -> compile-time register
// indices AND conflict-free bank groups; swizzle stays within one wave's
// 128-elem block so wave-lockstep makes it race-free), inv Q=16 (swizzled
// reads, plain writes), inv Q=128, fused final pass + normalize + store.
__global__ __launch_bounds__(512, 4) void fft_analytic_kernel(const float* __restrict__ x,
                                                              ushort* __restrict__ zc,
                                                              ushort* __restrict__ zs) {
    __shared__ __align__(16) float2 buf[T_LEN];   // 64 KiB
    const int tid = threadIdx.x;
    const int row = blockIdx.x;
    const float* xr = x + ((size_t)row << 13);

    // fwd pass Q=1024 fused with global load (x real; imag folds away)
    for (int s = 0; s < 2; ++s) {
        const int g = tid + (s << 9);
        float2 X[8], Y[8];
#pragma unroll
        for (int c = 0; c < 8; ++c) X[c] = make_float2(xr[g + (c << 10)], 0.f);
        float sn, cs;
        __sincosf(-(float)M_PI / 4096.f * (float)g, &sn, &cs);
        r8f(X, sn, cs, Y);
#pragma unroll
        for (int c = 0; c < 8; ++c) buf[g + (c << 10)] = Y[c];
    }
    __syncthreads();

    // fwd LDS pass Q=128
    {
        const float astep = -(float)M_PI / 512.f;
        for (int s = 0; s < 2; ++s) {
            const int g = tid + (s << 9);
            const int j = g & 127;
            const int i = ((g & ~127) << 3) | j;
            float2 xx[8], yy[8];
#pragma unroll
            for (int c = 0; c < 8; ++c) xx[c] = buf[i + c * 128];
            float sn, cs;
            __sincosf(astep * (float)j, &sn, &cs);
            r8f(xx, sn, cs, yy);
#pragma unroll
            for (int c = 0; c < 8; ++c) buf[i + c * 128] = yy[c];
        }
        __syncthreads();
    }

    // fwd LDS pass Q=16: plain reads, swizzled writes (slot = idx ^ 2c)
    {
        const float astep = -(float)M_PI / 64.f;
        for (int s = 0; s < 2; ++s) {
            const int g = tid + (s << 9);
            const int j = g & 15;
            const int i = ((g & ~15) << 3) | j;
            float2 xx[8], yy[8];
#pragma unroll
            for (int c = 0; c < 8; ++c) xx[c] = buf[i + c * 16];
            float sn, cs;
            __sincosf(astep * (float)j, &sn, &cs);
            r8f(xx, sn, cs, yy);
#pragma unroll
            for (int c = 0; c < 8; ++c) buf[(i + c * 16) ^ (2 * c)] = yy[c];
        }
        __syncthreads();
    }

    // register-local middle: thread owns elements [16*tid, 16*tid+16).
    // Element-float4 (8*tid+p) lives at slot4 (8*tid + (p^(tid&7))).
    {
        float2 v[16];
        float4* bb = (float4*)buf;
        const int K = tid & 7;
#pragma unroll
        for (int p = 0; p < 8; ++p) {
            float4 f = bb[8 * tid + (p ^ K)];
            v[2 * p]     = make_float2(f.x, f.y);
            v[2 * p + 1] = make_float2(f.z, f.w);
        }
        float2 xe[8], xo[8], E[8], O[8], t[8];
#pragma unroll
        for (int c = 0; c < 8; ++c) { xe[c] = v[2 * c]; xo[c] = v[2 * c + 1]; }
        r8f(xe, 0.f, 1.f, E);
        r8f(xo, -SIN8, COS8, O);
#pragma unroll
        for (int c = 0; c < 8; ++c) t[c] = cadd(E[c], O[c]);   // dist-1 + mask fuse
        r8i(t, 0.f, 1.f, xe);
        r8i(t, SIN8, COS8, xo);
#pragma unroll
        for (int p = 0; p < 8; ++p)
            bb[8 * tid + (p ^ K)] = make_float4(xe[p].x, xe[p].y, xo[p].x, xo[p].y);
    }
    __syncthreads();

    // inv LDS pass Q=16: swizzled reads, plain writes
    {
        const float astep = (float)M_PI / 64.f;
        for (int s = 0; s < 2; ++s) {
            const int g = tid + (s << 9);
            const int j = g & 15;
            const int i = ((g & ~15) << 3) | j;
            float2 xx[8], yy[8];
#pragma unroll
            for (int c = 0; c < 8; ++c) xx[c] = buf[(i + c * 16) ^ (2 * c)];
            float sn, cs;
            __sincosf(astep * (float)j, &sn, &cs);
            r8i(xx, sn, cs, yy);
#pragma unroll
            for (int c = 0; c < 8; ++c) buf[i + c * 16] = yy[c];
        }
        __syncthreads();
    }

    // inv LDS pass Q=128
    {
        const float astep = (float)M_PI / 512.f;
        for (int s = 0; s < 2; ++s) {
            const int g = tid + (s << 9);
            const int j = g & 127;
            const int i = ((g & ~127) << 3) | j;
            float2 xx[8], yy[8];
#pragma unroll
            for (int c = 0; c < 8; ++c) xx[c] = buf[i + c * 128];
            float sn, cs;
            __sincosf(astep * (float)j, &sn, &cs);
            r8i(xx, sn, cs, yy);
#pragma unroll
            for (int c = 0; c < 8; ++c) buf[i + c * 128] = yy[c];
        }
        __syncthreads();
    }

    // final inv pass Q=1024 fused with normalize + contiguous row-major store
    ushort* zcr = zc + ((size_t)row << 13);
    ushort* zsr = zs + ((size_t)row << 13);
    for (int s = 0; s < 2; ++s) {
        const int g = tid + (s << 9);
        float2 xx[8], yy[8];
#pragma unroll
        for (int c = 0; c < 8; ++c) xx[c] = buf[g + (c << 10)];
        float sn, cs;
        __sincosf((float)M_PI / 4096.f * (float)g, &sn, &cs);
        r8i(xx, sn, cs, yy);
#pragma unroll
        for (int c = 0; c < 8; ++c) {
            float2 vv = yy[c];
            float n2 = vv.x * vv.x + vv.y * vv.y;
            float cc = 1.f, ss = 0.f;
            if (n2 > 0.f) { float inv = rsqrtf(n2); cc = vv.x * inv; ss = vv.y * inv; }
            zcr[g + (c << 10)] = f2bf(cc);
            zsr[g + (c << 10)] = f2bf(ss);
        }
    }
}

// MFMA Gram partials. grid=(BATCH, NKCHUNK), block=512 (8 waves, 2/SIMD).
// Depth-2 register prefetch: each global load gets ~2 MFMA sections (~1000+
// cyc) to land before its LDS store (HBM latency ~900 cyc; depth-1 gave ~450).
__global__ __launch_bounds__(512, 2) void gram_kernel(const ushort* __restrict__ zc,
                                                      const ushort* __restrict__ zs,
                                                      __half2* __restrict__ partial) {
    const int b = blockIdx.x, kc = blockIdx.y;
    const int tid = threadIdx.x;
    const int wave = tid >> 6;
    const int wr = wave & 3, wcol = wave >> 2;
    const int lane31 = tid & 31;
    const int half = (tid >> 5) & 1;

    __shared__ __align__(16) ushort sZ[2 * SPLANE];

    f32x16 accRe[2], accIm[2];
#pragma unroll
    for (int v = 0; v < 2; ++v)
#pragma unroll
        for (int r = 0; r < 16; ++r) { accRe[v][r] = 0.f; accIm[v][r] = 0.f; }

    const size_t base = ((size_t)b * CHN) << 13;
    const int k0 = kc << 9;   // *512

    const ushort* srcs[4];
    int ldst[4];
#pragma unroll
    for (int q = 0; q < 4; ++q) {
        int id = tid + (q << 9);                   // 0..2047 = plane*1024 + rid*8 + ck
        int plane = id >> 10;
        int rid = (id >> 3) & 127;
        int ck = id & 7;
        srcs[q] = (plane ? zs : zc) + base + ((size_t)rid << 13) + (size_t)(k0 + ck * 8);
        ldst[q] = plane * SPLANE + rid * SROW + ck * 8;
    }

    uint4 pre[2][4];
#pragma unroll
    for (int q = 0; q < 4; ++q) pre[0][q] = *(const uint4*)srcs[q];
#pragma unroll
    for (int q = 0; q < 4; ++q) pre[1][q] = *(const uint4*)(srcs[q] + 64);

#pragma unroll
    for (int it = 0; it < 8; ++it) {
        __syncthreads();
#pragma unroll
        for (int q = 0; q < 4; ++q) *(uint4*)&sZ[ldst[q]] = pre[it & 1][q];
        if (it < 6) {
#pragma unroll
            for (int q = 0; q < 4; ++q)
                pre[it & 1][q] = *(const uint4*)(srcs[q] + (it + 2) * 64);
        }
        __syncthreads();
#pragma unroll
        for (int kb = 0; kb < 64; kb += 16) {
            const int aoff = (wr * 32 + lane31) * SROW + kb + half * 8;
            bf16x8 aC = *(const bf16x8*)&sZ[aoff];
            bf16x8 aS = *(const bf16x8*)&sZ[SPLANE + aoff];
            bf16x8 aCn;
#pragma unroll
            for (int r = 0; r < 8; ++r) aCn[r] = (short)(aC[r] ^ (short)0x8000);
            bf16x8 bC[2], bS[2];
#pragma unroll
            for (int v = 0; v < 2; ++v) {
                const int boff = (wcol * 64 + v * 32 + lane31) * SROW + kb + half * 8;
                bC[v] = *(const bf16x8*)&sZ[boff];
                bS[v] = *(const bf16x8*)&sZ[SPLANE + boff];
            }
            accRe[0] = __builtin_amdgcn_mfma_f32_32x32x16_bf16(aC,  bC[0], accRe[0], 0, 0, 0);
            accRe[1] = __builtin_amdgcn_mfma_f32_32x32x16_bf16(aC,  bC[1], accRe[1], 0, 0, 0);
            accIm[0] = __builtin_amdgcn_mfma_f32_32x32x16_bf16(aS,  bC[0], accIm[0], 0, 0, 0);
            accIm[1] = __builtin_amdgcn_mfma_f32_32x32x16_bf16(aS,  bC[1], accIm[1], 0, 0, 0);
            accRe[0] = __builtin_amdgcn_mfma_f32_32x32x16_bf16(aS,  bS[0], accRe[0], 0, 0, 0);
            accRe[1] = __builtin_amdgcn_mfma_f32_32x32x16_bf16(aS,  bS[1], accRe[1], 0, 0, 0);
            accIm[0] = __builtin_amdgcn_mfma_f32_32x32x16_bf16(aCn, bS[0], accIm[0], 0, 0, 0);
            accIm[1] = __builtin_amdgcn_mfma_f32_32x32x16_bf16(aCn, bS[1], accIm[1], 0, 0, 0);
        }
    }

    // C/D layout (verified m74/m101): col=lane&31, row=(reg&3)+8*(reg>>2)+4*(lane>>5)
    __half2* pb = partial + ((size_t)(kc * BATCH + b) << 14);
#pragma unroll
    for (int v = 0; v < 2; ++v)
#pragma unroll
        for (int r = 0; r < 16; ++r) {
            int rrow = (r & 3) + 8 * (r >> 2) + 4 * half;
            int i = wr * 32 + rrow;
            int j = wcol * 64 + v * 32 + lane31;
            pb[i * CHN + j] = __floats2half2_rn(accRe[v][r], accIm[v][r]);
        }
}

__global__ __launch_bounds__(256) void reduce_kernel(const __half2* __restrict__ partial,
                                                     float* __restrict__ out) {
    const size_t i = (size_t)blockIdx.x * 256 + threadIdx.x;
    const size_t n = (size_t)BATCH * CHN * CHN;
    if (i >= n) return;
    float re = 0.0f, im = 0.0f;
#pragma unroll
    for (int c = 0; c < NKCHUNK; ++c) {
        float2 p = __half22float2(partial[(size_t)c * n + i]);
        re += p.x;
        im += p.y;
    }
    out[i] = sqrtf(re * re + im * im) * (1.0f / (float)T_LEN);
}

extern "C" void kernel_launch(void* const* d_in, const int* in_sizes, int n_in,
                              void* d_out, int out_size, void* d_ws, size_t ws_size,
                              hipStream_t stream) {
    const float* x = (const float*)d_in[0];
    float* out = (float*)d_out;

    const size_t plane_elems = (size_t)BATCH * CHN * T_LEN;                 // 16.8M
    ushort* zc = (ushort*)d_ws;                                             // 33.55 MB
    ushort* zs = zc + plane_elems;                                          // +33.55 MB
    __half2* partial = (__half2*)((char*)d_ws + 2 * plane_elems * sizeof(ushort)); // +16.78 MB

    fft_analytic_kernel<<<BATCH * CHN, 512, 0, stream>>>(x, zc, zs);

    dim3 g2(BATCH, NKCHUNK);
    gram_kernel<<<g2, 512, 0, stream>>>(zc, zs, partial);

    const int n_out = BATCH * CHN * CHN;
    reduce_kernel<<<(n_out + 255) / 256, 256, 0, stream>>>(partial, out);
}

// Round 9
// 177.394 us; speedup vs baseline: 1.9267x; 1.0014x over previous
//
#include <hip/hip_runtime.h>
#include <hip/hip_fp16.h>
#include <math.h>

#define T_LEN 8192
#define CHN 128
#define BATCH 16
#define NKCHUNK 16   // k-chunk = 512 = 8 tiles of 64

typedef short bf16x8 __attribute__((ext_vector_type(8)));
typedef float f32x16 __attribute__((ext_vector_type(16)));

#define SIN8 0.3826834323650898f
#define COS8 0.9238795325112868f
#define SROW 72          // LDS row stride (ushorts) = 144 B, 16B-aligned
#define SPLANE (128 * SROW)

__device__ __forceinline__ ushort f2bf(float f) {
    unsigned u = __float_as_uint(f);
    unsigned r = (u + 0x7fffu + ((u >> 16) & 1u)) >> 16;
    return (ushort)r;
}

// Barrier that drains ONLY LDS ops (lgkmcnt), leaving global prefetch loads
// in flight. __syncthreads() emits s_waitcnt vmcnt(0) before s_barrier, which
// drains the depth-2 prefetch every iteration — the gram 66-us stall (R8 pm).
__device__ __forceinline__ void barrier_lds_only() {
    asm volatile("s_waitcnt lgkmcnt(0)" ::: "memory");
    __builtin_amdgcn_s_barrier();
}

__device__ __forceinline__ float2 cadd(float2 a, float2 b) { return make_float2(a.x + b.x, a.y + b.y); }
__device__ __forceinline__ float2 csub(float2 a, float2 b) { return make_float2(a.x - b.x, a.y - b.y); }
__device__ __forceinline__ float2 cmul(float2 a, float2 b) {
    return make_float2(a.x * b.x - a.y * b.y, a.x * b.y + a.y * b.x);
}

__device__ __forceinline__ void r4f(float2 x0, float2 x1, float2 x2, float2 x3,
                                    float2 wa, float2 wb, float2 wc,
                                    float2& y0, float2& y1, float2& y2, float2& y3) {
    float2 t0 = cadd(x0, x2), t1 = csub(x0, x2);
    float2 t2 = cadd(x1, x3), t3 = csub(x1, x3);
    y0 = cadd(t0, t2);
    y1 = cmul(csub(t0, t2), wb);
    y2 = cmul(make_float2(t1.x + t3.y, t1.y - t3.x), wa);
    y3 = cmul(make_float2(t1.x - t3.y, t1.y + t3.x), wc);
}

__device__ __forceinline__ void r4i(float2 x0, float2 x1, float2 x2, float2 x3,
                                    float2 wa, float2 wb, float2 wc,
                                    float2& y0, float2& y1, float2& y2, float2& y3) {
    float2 a1 = cmul(x1, wb);
    float2 a2 = cmul(x2, wa);
    float2 a3 = cmul(x3, wc);
    float2 u0 = cadd(x0, a1), u1 = csub(x0, a1);
    float2 p = cadd(a2, a3);
    float2 m = make_float2(-(a2.y - a3.y), a2.x - a3.x);
    y0 = cadd(u0, p); y2 = csub(u0, p);
    y1 = cadd(u1, m); y3 = csub(u1, m);
}

__device__ __forceinline__ void r8f(const float2* x, float sn, float cs, float2* y) {
    const float r22 = 0.70710678118654752f;
    float2 w1 = make_float2(cs, sn);
    float2 w2 = make_float2(cs * cs - sn * sn, 2.f * cs * sn);
    float2 w4 = cmul(w2, w2);
    float2 w6 = cmul(w4, w2);
    float2 u0 = cadd(x[0], x[4]), u1 = cadd(x[1], x[5]), u2 = cadd(x[2], x[6]), u3 = cadd(x[3], x[7]);
    float2 e0 = cmul(csub(x[0], x[4]), w1);
    float2 e1 = cmul(csub(x[1], x[5]), w1);
    float2 e2 = cmul(csub(x[2], x[6]), w1);
    float2 e3 = cmul(csub(x[3], x[7]), w1);
    float2 v0 = e0;
    float2 v1 = make_float2(r22 * (e1.x + e1.y), r22 * (e1.y - e1.x));
    float2 v2 = make_float2(e2.y, -e2.x);
    float2 v3 = make_float2(r22 * (e3.y - e3.x), -r22 * (e3.x + e3.y));
    r4f(u0, u1, u2, u3, w2, w4, w6, y[0], y[1], y[2], y[3]);
    r4f(v0, v1, v2, v3, w2, w4, w6, y[4], y[5], y[6], y[7]);
}

__device__ __forceinline__ void r8i(const float2* x, float sn, float cs, float2* y) {
    const float r22 = 0.70710678118654752f;
    float2 w1 = make_float2(cs, sn);
    float2 w2 = make_float2(cs * cs - sn * sn, 2.f * cs * sn);
    float2 w4 = cmul(w2, w2);
    float2 w6 = cmul(w4, w2);
    float2 g0, g1, g2, g3, g4, g5, g6, g7;
    r4i(x[0], x[1], x[2], x[3], w2, w4, w6, g0, g1, g2, g3);
    r4i(x[4], x[5], x[6], x[7], w2, w4, w6, g4, g5, g6, g7);
    float2 t0 = cmul(g4, w1);
    float2 e1 = cmul(g5, w1);
    float2 e2 = cmul(g6, w1);
    float2 e3 = cmul(g7, w1);
    float2 t1 = make_float2(r22 * (e1.x - e1.y), r22 * (e1.x + e1.y));
    float2 t2 = make_float2(-e2.y, e2.x);
    float2 t3 = make_float2(-r22 * (e3.x + e3.y), r22 * (e3.x - e3.y));
    y[0] = cadd(g0, t0); y[4] = csub(g0, t0);
    y[1] = cadd(g1, t1); y[5] = csub(g1, t1);
    y[2] = cadd(g2, t2); y[6] = csub(g2, t2);
    y[3] = cadd(g3, t3); y[7] = csub(g3, t3);
}

// One block per (b,c) row. Fused load+fwd radix-8 (Q=1024), fwd Q=128 pass,
// fwd Q=16 pass (plain reads, XOR-swizzled writes), register-local middle
// (swizzled slots, compile-time register indices), inv Q=16 (swizzled reads),
// inv Q=128, fused final pass + normalize + store. UNCHANGED from R8.
__global__ __launch_bounds__(512, 4) void fft_analytic_kernel(const float* __restrict__ x,
                                                              ushort* __restrict__ zc,
                                                              ushort* __restrict__ zs) {
    __shared__ __align__(16) float2 buf[T_LEN];   // 64 KiB
    const int tid = threadIdx.x;
    const int row = blockIdx.x;
    const float* xr = x + ((size_t)row << 13);

    // fwd pass Q=1024 fused with global load (x real; imag folds away)
    for (int s = 0; s < 2; ++s) {
        const int g = tid + (s << 9);
        float2 X[8], Y[8];
#pragma unroll
        for (int c = 0; c < 8; ++c) X[c] = make_float2(xr[g + (c << 10)], 0.f);
        float sn, cs;
        __sincosf(-(float)M_PI / 4096.f * (float)g, &sn, &cs);
        r8f(X, sn, cs, Y);
#pragma unroll
        for (int c = 0; c < 8; ++c) buf[g + (c << 10)] = Y[c];
    }
    __syncthreads();

    // fwd LDS pass Q=128
    {
        const float astep = -(float)M_PI / 512.f;
        for (int s = 0; s < 2; ++s) {
            const int g = tid + (s << 9);
            const int j = g & 127;
            const int i = ((g & ~127) << 3) | j;
            float2 xx[8], yy[8];
#pragma unroll
            for (int c = 0; c < 8; ++c) xx[c] = buf[i + c * 128];
            float sn, cs;
            __sincosf(astep * (float)j, &sn, &cs);
            r8f(xx, sn, cs, yy);
#pragma unroll
            for (int c = 0; c < 8; ++c) buf[i + c * 128] = yy[c];
        }
        __syncthreads();
    }

    // fwd LDS pass Q=16: plain reads, swizzled writes (slot = idx ^ 2c)
    {
        const float astep = -(float)M_PI / 64.f;
        for (int s = 0; s < 2; ++s) {
            const int g = tid + (s << 9);
            const int j = g & 15;
            const int i = ((g & ~15) << 3) | j;
            float2 xx[8], yy[8];
#pragma unroll
            for (int c = 0; c < 8; ++c) xx[c] = buf[i + c * 16];
            float sn, cs;
            __sincosf(astep * (float)j, &sn, &cs);
            r8f(xx, sn, cs, yy);
#pragma unroll
            for (int c = 0; c < 8; ++c) buf[(i + c * 16) ^ (2 * c)] = yy[c];
        }
        __syncthreads();
    }

    // register-local middle: thread owns elements [16*tid, 16*tid+16).
    // Element-float4 (8*tid+p) lives at slot4 (8*tid + (p^(tid&7))).
    {
        float2 v[16];
        float4* bb = (float4*)buf;
        const int K = tid & 7;
#pragma unroll
        for (int p = 0; p < 8; ++p) {
            float4 f = bb[8 * tid + (p ^ K)];
            v[2 * p]     = make_float2(f.x, f.y);
            v[2 * p + 1] = make_float2(f.z, f.w);
        }
        float2 xe[8], xo[8], E[8], O[8], t[8];
#pragma unroll
        for (int c = 0; c < 8; ++c) { xe[c] = v[2 * c]; xo[c] = v[2 * c + 1]; }
        r8f(xe, 0.f, 1.f, E);
        r8f(xo, -SIN8, COS8, O);
#pragma unroll
        for (int c = 0; c < 8; ++c) t[c] = cadd(E[c], O[c]);   // dist-1 + mask fuse
        r8i(t, 0.f, 1.f, xe);
        r8i(t, SIN8, COS8, xo);
#pragma unroll
        for (int p = 0; p < 8; ++p)
            bb[8 * tid + (p ^ K)] = make_float4(xe[p].x, xe[p].y, xo[p].x, xo[p].y);
    }
    __syncthreads();

    // inv LDS pass Q=16: swizzled reads, plain writes
    {
        const float astep = (float)M_PI / 64.f;
        for (int s = 0; s < 2; ++s) {
            const int g = tid + (s << 9);
            const int j = g & 15;
            const int i = ((g & ~15) << 3) | j;
            float2 xx[8], yy[8];
#pragma unroll
            for (int c = 0; c < 8; ++c) xx[c] = buf[(i + c * 16) ^ (2 * c)];
            float sn, cs;
            __sincosf(astep * (float)j, &sn, &cs);
            r8i(xx, sn, cs, yy);
#pragma unroll
            for (int c = 0; c < 8; ++c) buf[i + c * 16] = yy[c];
        }
        __syncthreads();
    }

    // inv LDS pass Q=128
    {
        const float astep = (float)M_PI / 512.f;
        for (int s = 0; s < 2; ++s) {
            const int g = tid + (s << 9);
            const int j = g & 127;
            const int i = ((g & ~127) << 3) | j;
            float2 xx[8], yy[8];
#pragma unroll
            for (int c = 0; c < 8; ++c) xx[c] = buf[i + c * 128];
            float sn, cs;
            __sincosf(astep * (float)j, &sn, &cs);
            r8i(xx, sn, cs, yy);
#pragma unroll
            for (int c = 0; c < 8; ++c) buf[i + c * 128] = yy[c];
        }
        __syncthreads();
    }

    // final inv pass Q=1024 fused with normalize + contiguous row-major store
    ushort* zcr = zc + ((size_t)row << 13);
    ushort* zsr = zs + ((size_t)row << 13);
    for (int s = 0; s < 2; ++s) {
        const int g = tid + (s << 9);
        float2 xx[8], yy[8];
#pragma unroll
        for (int c = 0; c < 8; ++c) xx[c] = buf[g + (c << 10)];
        float sn, cs;
        __sincosf((float)M_PI / 4096.f * (float)g, &sn, &cs);
        r8i(xx, sn, cs, yy);
#pragma unroll
        for (int c = 0; c < 8; ++c) {
            float2 vv = yy[c];
            float n2 = vv.x * vv.x + vv.y * vv.y;
            float cc = 1.f, ss = 0.f;
            if (n2 > 0.f) { float inv = rsqrtf(n2); cc = vv.x * inv; ss = vv.y * inv; }
            zcr[g + (c << 10)] = f2bf(cc);
            zsr[g + (c << 10)] = f2bf(ss);
        }
    }
}

// MFMA Gram partials. grid=(BATCH, NKCHUNK), block=512 (8 waves, 2/SIMD).
// Depth-2 register prefetch + lgkm-only barriers: prefetch loads stay in
// flight across iterations (no per-iter vmcnt(0) drain). The ds_write's
// dependence on prefetched VGPRs gets the compiler's fine-grained vmcnt(N).
__global__ __launch_bounds__(512, 2) void gram_kernel(const ushort* __restrict__ zc,
                                                      const ushort* __restrict__ zs,
                                                      __half2* __restrict__ partial) {
    const int b = blockIdx.x, kc = blockIdx.y;
    const int tid = threadIdx.x;
    const int wave = tid >> 6;
    const int wr = wave & 3, wcol = wave >> 2;
    const int lane31 = tid & 31;
    const int half = (tid >> 5) & 1;

    __shared__ __align__(16) ushort sZ[2 * SPLANE];

    f32x16 accRe[2], accIm[2];
#pragma unroll
    for (int v = 0; v < 2; ++v)
#pragma unroll
        for (int r = 0; r < 16; ++r) { accRe[v][r] = 0.f; accIm[v][r] = 0.f; }

    const size_t base = ((size_t)b * CHN) << 13;
    const int k0 = kc << 9;   // *512

    const ushort* srcs[4];
    int ldst[4];
#pragma unroll
    for (int q = 0; q < 4; ++q) {
        int id = tid + (q << 9);                   // 0..2047 = plane*1024 + rid*8 + ck
        int plane = id >> 10;
        int rid = (id >> 3) & 127;
        int ck = id & 7;
        srcs[q] = (plane ? zs : zc) + base + ((size_t)rid << 13) + (size_t)(k0 + ck * 8);
        ldst[q] = plane * SPLANE + rid * SROW + ck * 8;
    }

    uint4 pre[2][4];
#pragma unroll
    for (int q = 0; q < 4; ++q) pre[0][q] = *(const uint4*)srcs[q];
#pragma unroll
    for (int q = 0; q < 4; ++q) pre[1][q] = *(const uint4*)(srcs[q] + 64);

#pragma unroll
    for (int it = 0; it < 8; ++it) {
        barrier_lds_only();                         // prev iter's ds_reads done
#pragma unroll
        for (int q = 0; q < 4; ++q) *(uint4*)&sZ[ldst[q]] = pre[it & 1][q];
        if (it < 6) {
#pragma unroll
            for (int q = 0; q < 4; ++q)
                pre[it & 1][q] = *(const uint4*)(srcs[q] + (it + 2) * 64);
        }
        barrier_lds_only();                         // ds_writes visible; vmem stays in flight
#pragma unroll
        for (int kb = 0; kb < 64; kb += 16) {
            const int aoff = (wr * 32 + lane31) * SROW + kb + half * 8;
            bf16x8 aC = *(const bf16x8*)&sZ[aoff];
            bf16x8 aS = *(const bf16x8*)&sZ[SPLANE + aoff];
            bf16x8 aCn;
#pragma unroll
            for (int r = 0; r < 8; ++r) aCn[r] = (short)(aC[r] ^ (short)0x8000);
            bf16x8 bC[2], bS[2];
#pragma unroll
            for (int v = 0; v < 2; ++v) {
                const int boff = (wcol * 64 + v * 32 + lane31) * SROW + kb + half * 8;
                bC[v] = *(const bf16x8*)&sZ[boff];
                bS[v] = *(const bf16x8*)&sZ[SPLANE + boff];
            }
            accRe[0] = __builtin_amdgcn_mfma_f32_32x32x16_bf16(aC,  bC[0], accRe[0], 0, 0, 0);
            accRe[1] = __builtin_amdgcn_mfma_f32_32x32x16_bf16(aC,  bC[1], accRe[1], 0, 0, 0);
            accIm[0] = __builtin_amdgcn_mfma_f32_32x32x16_bf16(aS,  bC[0], accIm[0], 0, 0, 0);
            accIm[1] = __builtin_amdgcn_mfma_f32_32x32x16_bf16(aS,  bC[1], accIm[1], 0, 0, 0);
            accRe[0] = __builtin_amdgcn_mfma_f32_32x32x16_bf16(aS,  bS[0], accRe[0], 0, 0, 0);
            accRe[1] = __builtin_amdgcn_mfma_f32_32x32x16_bf16(aS,  bS[1], accRe[1], 0, 0, 0);
            accIm[0] = __builtin_amdgcn_mfma_f32_32x32x16_bf16(aCn, bS[0], accIm[0], 0, 0, 0);
            accIm[1] = __builtin_amdgcn_mfma_f32_32x32x16_bf16(aCn, bS[1], accIm[1], 0, 0, 0);
        }
    }

    // C/D layout (verified m74/m101): col=lane&31, row=(reg&3)+8*(reg>>2)+4*(lane>>5)
    __half2* pb = partial + ((size_t)(kc * BATCH + b) << 14);
#pragma unroll
    for (int v = 0; v < 2; ++v)
#pragma unroll
        for (int r = 0; r < 16; ++r) {
            int rrow = (r & 3) + 8 * (r >> 2) + 4 * half;
            int i = wr * 32 + rrow;
            int j = wcol * 64 + v * 32 + lane31;
            pb[i * CHN + j] = __floats2half2_rn(accRe[v][r], accIm[v][r]);
        }
}

__global__ __launch_bounds__(256) void reduce_kernel(const __half2* __restrict__ partial,
                                                     float* __restrict__ out) {
    const size_t i = (size_t)blockIdx.x * 256 + threadIdx.x;
    const size_t n = (size_t)BATCH * CHN * CHN;
    if (i >= n) return;
    float re = 0.0f, im = 0.0f;
#pragma unroll
    for (int c = 0; c < NKCHUNK; ++c) {
        float2 p = __half22float2(partial[(size_t)c * n + i]);
        re += p.x;
        im += p.y;
    }
    out[i] = sqrtf(re * re + im * im) * (1.0f / (float)T_LEN);
}

extern "C" void kernel_launch(void* const* d_in, const int* in_sizes, int n_in,
                              void* d_out, int out_size, void* d_ws, size_t ws_size,
                              hipStream_t stream) {
    const float* x = (const float*)d_in[0];
    float* out = (float*)d_out;

    const size_t plane_elems = (size_t)BATCH * CHN * T_LEN;                 // 16.8M
    ushort* zc = (ushort*)d_ws;                                             // 33.55 MB
    ushort* zs = zc + plane_elems;                                          // +33.55 MB
    __half2* partial = (__half2*)((char*)d_ws + 2 * plane_elems * sizeof(ushort)); // +16.78 MB

    fft_analytic_kernel<<<BATCH * CHN, 512, 0, stream>>>(x, zc, zs);

    dim3 g2(BATCH, NKCHUNK);
    gram_kernel<<<g2, 512, 0, stream>>>(zc, zs, partial);

    const int n_out = BATCH * CHN * CHN;
    reduce_kernel<<<(n_out + 255) / 256, 256, 0, stream>>>(partial, out);
}